// Round 1
// 10172.120 us; speedup vs baseline: 1.8580x; 1.8580x over previous
//
#include <hip/hip_runtime.h>
#include <math.h>

#define D_MODEL 768
#define N_LAYER 8
#define D_INNER 1536
#define D_STATE 16
#define DT_RANK 48
#define D_CONV  4
#define BATCH   4
#define SEQLEN  1024
#define NTOK    (BATCH*SEQLEN)      // 4096 token rows
#define DBC_W   (DT_RANK + 2*D_STATE)  // 80
#define NC      32                  // scan chunks per sequence
#define CHUNK_T (SEQLEN/NC)         // 32 timesteps per chunk

// ---------------------------------------------------------------------------
// LayerNorm + residual update.  One block per token row (768 elems, 256 thr).
// first=1: resid = x + pos (layer 0).  first=0: resid += hh (prev hidden).
// Writes normalized output into hh (in-place reuse; safe within block).
// ---------------------------------------------------------------------------
__global__ __launch_bounds__(256) void ln_kernel(
    const float* __restrict__ x, const float* __restrict__ pos,
    float* __restrict__ resid, float* __restrict__ hh,
    const float* __restrict__ w, const float* __restrict__ b, int first) {
  int row = blockIdx.x;
  int tid = threadIdx.x;
  int base = row * D_MODEL;
  __shared__ float red[256];
  __shared__ float s_mu, s_rs;
  float v[3];
#pragma unroll
  for (int i = 0; i < 3; ++i) {
    int c = tid + i * 256;
    float r;
    if (first) r = x[base + c] + pos[base + c];
    else       r = resid[base + c] + hh[base + c];
    resid[base + c] = r;
    v[i] = r;
  }
  float s = v[0] + v[1] + v[2];
  red[tid] = s; __syncthreads();
  for (int off = 128; off > 0; off >>= 1) {
    if (tid < off) red[tid] += red[tid + off];
    __syncthreads();
  }
  if (tid == 0) s_mu = red[0] / D_MODEL;
  __syncthreads();
  float mu = s_mu;
  float q = 0.f;
#pragma unroll
  for (int i = 0; i < 3; ++i) { float d = v[i] - mu; q += d * d; }
  __syncthreads();
  red[tid] = q; __syncthreads();
  for (int off = 128; off > 0; off >>= 1) {
    if (tid < off) red[tid] += red[tid + off];
    __syncthreads();
  }
  if (tid == 0) s_rs = rsqrtf(red[0] / D_MODEL + 1e-5f);
  __syncthreads();
  float rs = s_rs;
#pragma unroll
  for (int i = 0; i < 3; ++i) {
    int c = tid + i * 256;
    hh[base + c] = (v[i] - mu) * rs * w[c] + b[c];
  }
}

// ---------------------------------------------------------------------------
// C[M x N] = A[M x K] * B[N x K]^T   (all row-major, fp32)
// BM=BN=64, BK=16, 256 threads, 4x4 micro-tile per thread.
// Requires M%64==0, N%64==0, K%16==0.
// ---------------------------------------------------------------------------
__global__ __launch_bounds__(256) void gemm_abt(
    const float* __restrict__ A, const float* __restrict__ B,
    float* __restrict__ C, int M, int N, int K) {
  const int BM = 64, BN = 64, BK = 16, TM = 4, TN = 4;
  __shared__ float As[BK][BM + 1];
  __shared__ float Bs[BK][BN + 1];
  int brow = blockIdx.y * BM;
  int bcol = blockIdx.x * BN;
  int tid = threadIdx.x;
  int tr = (tid / (BN / TN)) * TM;   // [0,64) step 4
  int tc = (tid % (BN / TN)) * TN;
  float acc[TM][TN] = {};
  for (int k0 = 0; k0 < K; k0 += BK) {
    for (int i = tid; i < BM * BK; i += 256) {
      int r = i / BK, c = i % BK;
      As[c][r] = A[(size_t)(brow + r) * K + k0 + c];
    }
    for (int i = tid; i < BN * BK; i += 256) {
      int r = i / BK, c = i % BK;
      Bs[c][r] = B[(size_t)(bcol + r) * K + k0 + c];
    }
    __syncthreads();
#pragma unroll
    for (int kk = 0; kk < BK; ++kk) {
      float a[TM], bb[TN];
#pragma unroll
      for (int i = 0; i < TM; ++i) a[i] = As[kk][tr + i];
#pragma unroll
      for (int j = 0; j < TN; ++j) bb[j] = Bs[kk][tc + j];
#pragma unroll
      for (int i = 0; i < TM; ++i)
#pragma unroll
        for (int j = 0; j < TN; ++j) acc[i][j] += a[i] * bb[j];
    }
    __syncthreads();
  }
  for (int i = 0; i < TM; ++i)
    for (int j = 0; j < TN; ++j)
      C[(size_t)(brow + tr + i) * N + bcol + tc + j] = acc[i][j];
}

// ---------------------------------------------------------------------------
// Causal depthwise conv (width 4) + bias + SiLU.  xm = xz[..., :D_INNER].
// ---------------------------------------------------------------------------
__global__ __launch_bounds__(256) void conv_silu_kernel(
    const float* __restrict__ xz, const float* __restrict__ cw,
    const float* __restrict__ cb, float* __restrict__ u) {
  int idx = blockIdx.x * 256 + threadIdx.x;
  if (idx >= NTOK * D_INNER) return;
  int c = idx % D_INNER;
  int t = (idx / D_INNER) % SEQLEN;
  int b = idx / (D_INNER * SEQLEN);
  float acc = cb[c];
#pragma unroll
  for (int k = 0; k < D_CONV; ++k) {
    int tt = t + k - (D_CONV - 1);
    if (tt >= 0)
      acc += xz[(size_t)(b * SEQLEN + tt) * (2 * D_INNER) + c] * cw[c * D_CONV + k];
  }
  float sig = 1.f / (1.f + __expf(-acc));
  u[idx] = acc * sig;
}

// ---------------------------------------------------------------------------
// dbc[row, e] = sum_d u[row,d] * x_proj[e,d]      (e < 80, K = 1536)
// ---------------------------------------------------------------------------
__global__ __launch_bounds__(256) void xproj_kernel(
    const float* __restrict__ u, const float* __restrict__ xp,
    float* __restrict__ dbc) {
  int idx = blockIdx.x * 256 + threadIdx.x;
  if (idx >= NTOK * DBC_W) return;
  int e = idx % DBC_W;
  int row = idx / DBC_W;
  const float4* u4 = (const float4*)(u + (size_t)row * D_INNER);
  const float4* w4 = (const float4*)(xp + (size_t)e * D_INNER);
  float acc = 0.f;
#pragma unroll 4
  for (int k = 0; k < D_INNER / 4; ++k) {
    float4 a = u4[k], b = w4[k];
    acc += a.x * b.x + a.y * b.y + a.z * b.z + a.w * b.w;
  }
  dbc[idx] = acc;
}

// ---------------------------------------------------------------------------
// dt[row, d] = softplus( sum_r dbc[row,r] * dt_w[d,r] + dt_b[d] )
// ---------------------------------------------------------------------------
__global__ __launch_bounds__(256) void dt_kernel(
    const float* __restrict__ dbc, const float* __restrict__ dtw,
    const float* __restrict__ dtb, float* __restrict__ dt) {
  int idx = blockIdx.x * 256 + threadIdx.x;
  if (idx >= NTOK * D_INNER) return;
  int d = idx % D_INNER;
  int row = idx / D_INNER;
  const float* r = dbc + (size_t)row * DBC_W;
  const float* w = dtw + (size_t)d * DT_RANK;
  float acc = dtb[d];
#pragma unroll
  for (int k = 0; k < DT_RANK; ++k) acc += r[k] * w[k];
  float sp = (acc > 20.f) ? acc : log1pf(__expf(acc));
  dt[idx] = sp;
}

// ---------------------------------------------------------------------------
// Blocked selective scan, phase 1.
// One thread per (b, chunk, d).  Scans its CHUNK_T steps from h=0, emitting
// the chunk-final partial state S[b][c][s][d] and the chunk dt-sum.
// Layout [b][c][s][d]: d innermost for coalescing in all three phases.
// ---------------------------------------------------------------------------
__global__ __launch_bounds__(256) void scan_chunk1(
    const float* __restrict__ dty, const float* __restrict__ u,
    const float* __restrict__ dbc, const float* __restrict__ A_log,
    float* __restrict__ S, float* __restrict__ dtsum) {
  int g = blockIdx.x * 256 + threadIdx.x;
  if (g >= BATCH * NC * D_INNER) return;
  int d = g % D_INNER;
  int c = (g / D_INNER) % NC;
  int b = g / (D_INNER * NC);
  float A[D_STATE];
#pragma unroll
  for (int s = 0; s < D_STATE; ++s) A[s] = -__expf(A_log[d * D_STATE + s]);
  float h[D_STATE];
#pragma unroll
  for (int s = 0; s < D_STATE; ++s) h[s] = 0.f;
  float dts = 0.f;
  int t0 = c * CHUNK_T;
  for (int t = t0; t < t0 + CHUNK_T; ++t) {
    size_t rowb = (size_t)b * SEQLEN + t;
    float dtv = dty[rowb * D_INNER + d];
    float uv  = u[rowb * D_INNER + d];
    const float* bc = dbc + rowb * DBC_W;
    float dtu = dtv * uv;
    dts += dtv;
#pragma unroll
    for (int s = 0; s < D_STATE; ++s) {
      float da = __expf(dtv * A[s]);
      h[s] = da * h[s] + dtu * bc[DT_RANK + s];
    }
  }
  size_t base = (((size_t)b * NC + c) * D_STATE) * D_INNER + d;
#pragma unroll
  for (int s = 0; s < D_STATE; ++s) S[base + (size_t)s * D_INNER] = h[s];
  dtsum[((size_t)b * NC + c) * D_INNER + d] = dts;
}

// ---------------------------------------------------------------------------
// Blocked selective scan, phase 2 (serial chunk combine, tiny).
// One thread per (b, d).  h_in[c+1] = exp(A * dtsum[c]) * h_in[c] + S[c].
// Overwrites S[b][c][s][d] in place with h_in for chunk c.
// ---------------------------------------------------------------------------
__global__ __launch_bounds__(256) void scan_combine(
    float* __restrict__ S, const float* __restrict__ dtsum,
    const float* __restrict__ A_log) {
  int g = blockIdx.x * 256 + threadIdx.x;
  if (g >= BATCH * D_INNER) return;
  int b = g / D_INNER, d = g % D_INNER;
  float A[D_STATE];
#pragma unroll
  for (int s = 0; s < D_STATE; ++s) A[s] = -__expf(A_log[d * D_STATE + s]);
  float h[D_STATE];
#pragma unroll
  for (int s = 0; s < D_STATE; ++s) h[s] = 0.f;
  for (int c = 0; c < NC; ++c) {
    size_t base = (((size_t)b * NC + c) * D_STATE) * D_INNER + d;
    float dts = dtsum[((size_t)b * NC + c) * D_INNER + d];
#pragma unroll
    for (int s = 0; s < D_STATE; ++s) {
      size_t off = base + (size_t)s * D_INNER;
      float Sv = S[off];
      S[off] = h[s];                       // h_in for chunk c
      h[s] = __expf(dts * A[s]) * h[s] + Sv;
    }
  }
}

// ---------------------------------------------------------------------------
// Blocked selective scan, phase 3.
// One thread per (b, chunk, d).  Re-scans its chunk starting from h_in
// (stored in S by phase 2), computes y, applies D-skip + SiLU(z) gating.
// Writes gated y over dty.
// ---------------------------------------------------------------------------
__global__ __launch_bounds__(256) void scan_chunk2(
    float* __restrict__ dty, const float* __restrict__ u,
    const float* __restrict__ dbc, const float* __restrict__ xz,
    const float* __restrict__ A_log, const float* __restrict__ Dv,
    const float* __restrict__ hin) {
  int g = blockIdx.x * 256 + threadIdx.x;
  if (g >= BATCH * NC * D_INNER) return;
  int d = g % D_INNER;
  int c = (g / D_INNER) % NC;
  int b = g / (D_INNER * NC);
  float A[D_STATE];
#pragma unroll
  for (int s = 0; s < D_STATE; ++s) A[s] = -__expf(A_log[d * D_STATE + s]);
  float Dval = Dv[d];
  float h[D_STATE];
  size_t hbase = (((size_t)b * NC + c) * D_STATE) * D_INNER + d;
#pragma unroll
  for (int s = 0; s < D_STATE; ++s) h[s] = hin[hbase + (size_t)s * D_INNER];
  int t0 = c * CHUNK_T;
  for (int t = t0; t < t0 + CHUNK_T; ++t) {
    size_t rowb = (size_t)b * SEQLEN + t;
    float dtv = dty[rowb * D_INNER + d];
    float uv  = u[rowb * D_INNER + d];
    const float* bc = dbc + rowb * DBC_W;
    float dtu = dtv * uv;
    float yv = 0.f;
#pragma unroll
    for (int s = 0; s < D_STATE; ++s) {
      float da = __expf(dtv * A[s]);
      h[s] = da * h[s] + dtu * bc[DT_RANK + s];
      yv += h[s] * bc[DT_RANK + D_STATE + s];
    }
    float zv = xz[rowb * (2 * D_INNER) + D_INNER + d];
    float sig = 1.f / (1.f + __expf(-zv));
    float yo = (yv + uv * Dval) * (zv * sig);
    dty[rowb * D_INNER + d] = yo;
  }
}

// ---------------------------------------------------------------------------
// Final: residual add + LN(normf) + LN(dec), last rtn tokens only.
// ---------------------------------------------------------------------------
__global__ __launch_bounds__(256) void final_kernel(
    const float* __restrict__ hh, const float* __restrict__ resid,
    const float* __restrict__ fw, const float* __restrict__ fb,
    const float* __restrict__ dw, const float* __restrict__ db,
    float* __restrict__ out, int rtn) {
  int rowo = blockIdx.x;                 // 0 .. BATCH*rtn-1
  int b = rowo / rtn;
  int t = SEQLEN - rtn + (rowo % rtn);
  int tid = threadIdx.x;
  size_t base = ((size_t)b * SEQLEN + t) * D_MODEL;
  __shared__ float red[256];
  __shared__ float s_mu1, s_rs1, s_mu2, s_rs2;
  float v[3];
#pragma unroll
  for (int i = 0; i < 3; ++i) {
    int c = tid + i * 256;
    v[i] = hh[base + c] + resid[base + c];
  }
  // --- LN 1 ---
  red[tid] = v[0] + v[1] + v[2]; __syncthreads();
  for (int off = 128; off > 0; off >>= 1) {
    if (tid < off) red[tid] += red[tid + off];
    __syncthreads();
  }
  if (tid == 0) s_mu1 = red[0] / D_MODEL;
  __syncthreads();
  float mu = s_mu1, q = 0.f;
#pragma unroll
  for (int i = 0; i < 3; ++i) { float dd = v[i] - mu; q += dd * dd; }
  __syncthreads();
  red[tid] = q; __syncthreads();
  for (int off = 128; off > 0; off >>= 1) {
    if (tid < off) red[tid] += red[tid + off];
    __syncthreads();
  }
  if (tid == 0) s_rs1 = rsqrtf(red[0] / D_MODEL + 1e-5f);
  __syncthreads();
  float rs = s_rs1;
#pragma unroll
  for (int i = 0; i < 3; ++i) {
    int c = tid + i * 256;
    v[i] = (v[i] - mu) * rs * fw[c] + fb[c];
  }
  // --- LN 2 ---
  __syncthreads();
  red[tid] = v[0] + v[1] + v[2]; __syncthreads();
  for (int off = 128; off > 0; off >>= 1) {
    if (tid < off) red[tid] += red[tid + off];
    __syncthreads();
  }
  if (tid == 0) s_mu2 = red[0] / D_MODEL;
  __syncthreads();
  mu = s_mu2; q = 0.f;
#pragma unroll
  for (int i = 0; i < 3; ++i) { float dd = v[i] - mu; q += dd * dd; }
  __syncthreads();
  red[tid] = q; __syncthreads();
  for (int off = 128; off > 0; off >>= 1) {
    if (tid < off) red[tid] += red[tid + off];
    __syncthreads();
  }
  if (tid == 0) s_rs2 = rsqrtf(red[0] / D_MODEL + 1e-5f);
  __syncthreads();
  rs = s_rs2;
#pragma unroll
  for (int i = 0; i < 3; ++i) {
    int c = tid + i * 256;
    out[(size_t)rowo * D_MODEL + c] = (v[i] - mu) * rs * dw[c] + db[c];
  }
}

// ---------------------------------------------------------------------------
extern "C" void kernel_launch(void* const* d_in, const int* in_sizes, int n_in,
                              void* d_out, int out_size, void* d_ws, size_t ws_size,
                              hipStream_t stream) {
  const float* x       = (const float*)d_in[0];
  const float* pos     = (const float*)d_in[1];
  const float* norm_w  = (const float*)d_in[2];
  const float* norm_b  = (const float*)d_in[3];
  const float* in_proj = (const float*)d_in[4];
  const float* conv_w  = (const float*)d_in[5];
  const float* conv_b  = (const float*)d_in[6];
  const float* x_proj  = (const float*)d_in[7];
  const float* dt_w    = (const float*)d_in[8];
  const float* dt_b    = (const float*)d_in[9];
  const float* A_log   = (const float*)d_in[10];
  const float* Dv      = (const float*)d_in[11];
  const float* out_proj= (const float*)d_in[12];
  const float* normf_w = (const float*)d_in[13];
  const float* normf_b = (const float*)d_in[14];
  const float* dec_w   = (const float*)d_in[15];
  const float* dec_b   = (const float*)d_in[16];
  int rtn = out_size / (BATCH * D_MODEL);   // return_token_num

  float* ws    = (float*)d_ws;
  float* resid = ws;                                 // NTOK*D_MODEL
  float* hh    = resid + (size_t)NTOK * D_MODEL;     // NTOK*D_MODEL (h / hidden)
  float* xz    = hh    + (size_t)NTOK * D_MODEL;     // NTOK*2*D_INNER
  float* u     = xz    + (size_t)NTOK * 2 * D_INNER; // NTOK*D_INNER
  float* dbc   = u     + (size_t)NTOK * D_INNER;     // NTOK*80
  float* dty   = dbc   + (size_t)NTOK * DBC_W;       // NTOK*D_INNER (dt then y)
  float* Sbuf  = dty   + (size_t)NTOK * D_INNER;     // BATCH*NC*D_STATE*D_INNER
  float* dtsum = Sbuf  + (size_t)BATCH * NC * D_STATE * D_INNER; // BATCH*NC*D_INNER

  for (int l = 0; l < N_LAYER; ++l) {
    ln_kernel<<<NTOK, 256, 0, stream>>>(x, pos, resid, hh,
        norm_w + l * D_MODEL, norm_b + l * D_MODEL, l == 0);

    dim3 g1(2 * D_INNER / 64, NTOK / 64);
    gemm_abt<<<g1, 256, 0, stream>>>(hh,
        in_proj + (size_t)l * 2 * D_INNER * D_MODEL, xz,
        NTOK, 2 * D_INNER, D_MODEL);

    conv_silu_kernel<<<(NTOK * D_INNER + 255) / 256, 256, 0, stream>>>(
        xz, conv_w + (size_t)l * D_INNER * D_CONV, conv_b + l * D_INNER, u);

    xproj_kernel<<<(NTOK * DBC_W + 255) / 256, 256, 0, stream>>>(
        u, x_proj + (size_t)l * DBC_W * D_INNER, dbc);

    dt_kernel<<<(NTOK * D_INNER + 255) / 256, 256, 0, stream>>>(
        dbc, dt_w + (size_t)l * D_INNER * DT_RANK, dt_b + l * D_INNER, dty);

    const float* Al = A_log + (size_t)l * D_INNER * D_STATE;
    int tot1 = BATCH * NC * D_INNER;
    scan_chunk1<<<(tot1 + 255) / 256, 256, 0, stream>>>(
        dty, u, dbc, Al, Sbuf, dtsum);
    scan_combine<<<(BATCH * D_INNER + 255) / 256, 256, 0, stream>>>(
        Sbuf, dtsum, Al);
    scan_chunk2<<<(tot1 + 255) / 256, 256, 0, stream>>>(
        dty, u, dbc, xz, Al, Dv + l * D_INNER, Sbuf);

    dim3 g2(D_MODEL / 64, NTOK / 64);
    gemm_abt<<<g2, 256, 0, stream>>>(dty,
        out_proj + (size_t)l * D_MODEL * D_INNER, hh,
        NTOK, D_MODEL, D_INNER);
  }

  final_kernel<<<BATCH * rtn, 256, 0, stream>>>(
      hh, resid, normf_w, normf_b, dec_w, dec_b, (float*)d_out, rtn);
}

// Round 2
// 7695.063 us; speedup vs baseline: 2.4562x; 1.3219x over previous
//
#include <hip/hip_runtime.h>
#include <math.h>

#define D_MODEL 768
#define N_LAYER 8
#define D_INNER 1536
#define D_STATE 16
#define DT_RANK 48
#define D_CONV  4
#define BATCH   4
#define SEQLEN  1024
#define NTOK    (BATCH*SEQLEN)      // 4096 token rows
#define DBC_W   (DT_RANK + 2*D_STATE)  // 80
#define NC      32                  // scan chunks per sequence
#define CHUNK_T (SEQLEN/NC)         // 32 timesteps per chunk

// ---------------------------------------------------------------------------
// LayerNorm + residual update.  One block per token row (768 elems, 256 thr).
// ---------------------------------------------------------------------------
__global__ __launch_bounds__(256) void ln_kernel(
    const float* __restrict__ x, const float* __restrict__ pos,
    float* __restrict__ resid, float* __restrict__ hh,
    const float* __restrict__ w, const float* __restrict__ b, int first) {
  int row = blockIdx.x;
  int tid = threadIdx.x;
  int base = row * D_MODEL;
  __shared__ float red[256];
  __shared__ float s_mu, s_rs;
  float v[3];
#pragma unroll
  for (int i = 0; i < 3; ++i) {
    int c = tid + i * 256;
    float r;
    if (first) r = x[base + c] + pos[base + c];
    else       r = resid[base + c] + hh[base + c];
    resid[base + c] = r;
    v[i] = r;
  }
  float s = v[0] + v[1] + v[2];
  red[tid] = s; __syncthreads();
  for (int off = 128; off > 0; off >>= 1) {
    if (tid < off) red[tid] += red[tid + off];
    __syncthreads();
  }
  if (tid == 0) s_mu = red[0] / D_MODEL;
  __syncthreads();
  float mu = s_mu;
  float q = 0.f;
#pragma unroll
  for (int i = 0; i < 3; ++i) { float d = v[i] - mu; q += d * d; }
  __syncthreads();
  red[tid] = q; __syncthreads();
  for (int off = 128; off > 0; off >>= 1) {
    if (tid < off) red[tid] += red[tid + off];
    __syncthreads();
  }
  if (tid == 0) s_rs = rsqrtf(red[0] / D_MODEL + 1e-5f);
  __syncthreads();
  float rs = s_rs;
#pragma unroll
  for (int i = 0; i < 3; ++i) {
    int c = tid + i * 256;
    hh[base + c] = (v[i] - mu) * rs * w[c] + b[c];
  }
}

// ---------------------------------------------------------------------------
// C[M x N] = A[M x K] * B[N x K]^T   (all row-major, fp32)
// BM=BN=128, BK=16, 256 threads, 8x8 micro-tile per thread in split form:
// rows {tr..tr+3, tr+64..tr+67}, cols {tc..tc+3, tc+64..tc+67}.
// Inner loop: 4x ds_read_b128 (conflict-free) + 64 FMA per kk -> VALU-bound.
// Requires M%128==0, N%128==0, K%16==0.
// ---------------------------------------------------------------------------
__global__ __launch_bounds__(256) void gemm_abt(
    const float* __restrict__ A, const float* __restrict__ B,
    float* __restrict__ C, int M, int N, int K) {
  const int BM = 128, BN = 128, BK = 16;
  __shared__ __align__(16) float As[BK][BM + 4];
  __shared__ __align__(16) float Bs[BK][BN + 4];
  int brow = blockIdx.y * BM;
  int bcol = blockIdx.x * BN;
  int tid = threadIdx.x;
  int tr = (tid / 16) * 4;   // 0..60
  int tc = (tid % 16) * 4;   // 0..60
  float acc[2][2][4][4] = {};   // [row-half][col-half][i][j]
  for (int k0 = 0; k0 < K; k0 += BK) {
    // stage: 128 rows x 16 k each for A and B; 2 float4 per thread per matrix
#pragma unroll
    for (int it = 0; it < 2; ++it) {
      int idx = tid + it * 256;          // 0..511
      int r  = idx >> 2;                 // 0..127
      int cq = (idx & 3) * 4;            // 0,4,8,12
      float4 a = *(const float4*)&A[(size_t)(brow + r) * K + k0 + cq];
      As[cq + 0][r] = a.x; As[cq + 1][r] = a.y;
      As[cq + 2][r] = a.z; As[cq + 3][r] = a.w;
      float4 b = *(const float4*)&B[(size_t)(bcol + r) * K + k0 + cq];
      Bs[cq + 0][r] = b.x; Bs[cq + 1][r] = b.y;
      Bs[cq + 2][r] = b.z; Bs[cq + 3][r] = b.w;
    }
    __syncthreads();
#pragma unroll
    for (int kk = 0; kk < BK; ++kk) {
      float4 a0 = *(const float4*)&As[kk][tr];
      float4 a1 = *(const float4*)&As[kk][tr + 64];
      float4 b0 = *(const float4*)&Bs[kk][tc];
      float4 b1 = *(const float4*)&Bs[kk][tc + 64];
      float ar[2][4] = {{a0.x, a0.y, a0.z, a0.w}, {a1.x, a1.y, a1.z, a1.w}};
      float br[2][4] = {{b0.x, b0.y, b0.z, b0.w}, {b1.x, b1.y, b1.z, b1.w}};
#pragma unroll
      for (int rh = 0; rh < 2; ++rh)
#pragma unroll
        for (int ch = 0; ch < 2; ++ch)
#pragma unroll
          for (int i = 0; i < 4; ++i)
#pragma unroll
            for (int j = 0; j < 4; ++j)
              acc[rh][ch][i][j] += ar[rh][i] * br[ch][j];
    }
    __syncthreads();
  }
#pragma unroll
  for (int rh = 0; rh < 2; ++rh)
#pragma unroll
    for (int i = 0; i < 4; ++i) {
      int row = brow + tr + rh * 64 + i;
#pragma unroll
      for (int ch = 0; ch < 2; ++ch) {
        float4 o = make_float4(acc[rh][ch][i][0], acc[rh][ch][i][1],
                               acc[rh][ch][i][2], acc[rh][ch][i][3]);
        *(float4*)&C[(size_t)row * N + bcol + tc + ch * 64] = o;
      }
    }
}

// ---------------------------------------------------------------------------
// Causal depthwise conv (width 4) + bias + SiLU.  xm = xz[..., :D_INNER].
// ---------------------------------------------------------------------------
__global__ __launch_bounds__(256) void conv_silu_kernel(
    const float* __restrict__ xz, const float* __restrict__ cw,
    const float* __restrict__ cb, float* __restrict__ u) {
  int idx = blockIdx.x * 256 + threadIdx.x;
  if (idx >= NTOK * D_INNER) return;
  int c = idx % D_INNER;
  int t = (idx / D_INNER) % SEQLEN;
  int b = idx / (D_INNER * SEQLEN);
  float acc = cb[c];
#pragma unroll
  for (int k = 0; k < D_CONV; ++k) {
    int tt = t + k - (D_CONV - 1);
    if (tt >= 0)
      acc += xz[(size_t)(b * SEQLEN + tt) * (2 * D_INNER) + c] * cw[c * D_CONV + k];
  }
  float sig = 1.f / (1.f + __expf(-acc));
  u[idx] = acc * sig;
}

// ---------------------------------------------------------------------------
// dbc[row, e] = sum_d u[row,d] * x_proj[e,d]      (e < 80, K = 1536)
// ---------------------------------------------------------------------------
__global__ __launch_bounds__(256) void xproj_kernel(
    const float* __restrict__ u, const float* __restrict__ xp,
    float* __restrict__ dbc) {
  int idx = blockIdx.x * 256 + threadIdx.x;
  if (idx >= NTOK * DBC_W) return;
  int e = idx % DBC_W;
  int row = idx / DBC_W;
  const float4* u4 = (const float4*)(u + (size_t)row * D_INNER);
  const float4* w4 = (const float4*)(xp + (size_t)e * D_INNER);
  float acc = 0.f;
#pragma unroll 4
  for (int k = 0; k < D_INNER / 4; ++k) {
    float4 a = u4[k], b = w4[k];
    acc += a.x * b.x + a.y * b.y + a.z * b.z + a.w * b.w;
  }
  dbc[idx] = acc;
}

// ---------------------------------------------------------------------------
// dt[row, d] = softplus( sum_r dbc[row,r] * dt_w[d,r] + dt_b[d] )
// ---------------------------------------------------------------------------
__global__ __launch_bounds__(256) void dt_kernel(
    const float* __restrict__ dbc, const float* __restrict__ dtw,
    const float* __restrict__ dtb, float* __restrict__ dt) {
  int idx = blockIdx.x * 256 + threadIdx.x;
  if (idx >= NTOK * D_INNER) return;
  int d = idx % D_INNER;
  int row = idx / D_INNER;
  const float* r = dbc + (size_t)row * DBC_W;
  const float* w = dtw + (size_t)d * DT_RANK;
  float acc = dtb[d];
#pragma unroll
  for (int k = 0; k < DT_RANK; ++k) acc += r[k] * w[k];
  float sp = (acc > 20.f) ? acc : log1pf(__expf(acc));
  dt[idx] = sp;
}

// ---------------------------------------------------------------------------
// Blocked selective scan, phase 1.
// ---------------------------------------------------------------------------
__global__ __launch_bounds__(256) void scan_chunk1(
    const float* __restrict__ dty, const float* __restrict__ u,
    const float* __restrict__ dbc, const float* __restrict__ A_log,
    float* __restrict__ S, float* __restrict__ dtsum) {
  int g = blockIdx.x * 256 + threadIdx.x;
  if (g >= BATCH * NC * D_INNER) return;
  int d = g % D_INNER;
  int c = (g / D_INNER) % NC;
  int b = g / (D_INNER * NC);
  float A[D_STATE];
#pragma unroll
  for (int s = 0; s < D_STATE; ++s) A[s] = -__expf(A_log[d * D_STATE + s]);
  float h[D_STATE];
#pragma unroll
  for (int s = 0; s < D_STATE; ++s) h[s] = 0.f;
  float dts = 0.f;
  int t0 = c * CHUNK_T;
  for (int t = t0; t < t0 + CHUNK_T; ++t) {
    size_t rowb = (size_t)b * SEQLEN + t;
    float dtv = dty[rowb * D_INNER + d];
    float uv  = u[rowb * D_INNER + d];
    const float* bc = dbc + rowb * DBC_W;
    float dtu = dtv * uv;
    dts += dtv;
#pragma unroll
    for (int s = 0; s < D_STATE; ++s) {
      float da = __expf(dtv * A[s]);
      h[s] = da * h[s] + dtu * bc[DT_RANK + s];
    }
  }
  size_t base = (((size_t)b * NC + c) * D_STATE) * D_INNER + d;
#pragma unroll
  for (int s = 0; s < D_STATE; ++s) S[base + (size_t)s * D_INNER] = h[s];
  dtsum[((size_t)b * NC + c) * D_INNER + d] = dts;
}

// ---------------------------------------------------------------------------
// Blocked selective scan, phase 2 (serial chunk combine, tiny).
// ---------------------------------------------------------------------------
__global__ __launch_bounds__(256) void scan_combine(
    float* __restrict__ S, const float* __restrict__ dtsum,
    const float* __restrict__ A_log) {
  int g = blockIdx.x * 256 + threadIdx.x;
  if (g >= BATCH * D_INNER) return;
  int b = g / D_INNER, d = g % D_INNER;
  float A[D_STATE];
#pragma unroll
  for (int s = 0; s < D_STATE; ++s) A[s] = -__expf(A_log[d * D_STATE + s]);
  float h[D_STATE];
#pragma unroll
  for (int s = 0; s < D_STATE; ++s) h[s] = 0.f;
  for (int c = 0; c < NC; ++c) {
    size_t base = (((size_t)b * NC + c) * D_STATE) * D_INNER + d;
    float dts = dtsum[((size_t)b * NC + c) * D_INNER + d];
#pragma unroll
    for (int s = 0; s < D_STATE; ++s) {
      size_t off = base + (size_t)s * D_INNER;
      float Sv = S[off];
      S[off] = h[s];                       // h_in for chunk c
      h[s] = __expf(dts * A[s]) * h[s] + Sv;
    }
  }
}

// ---------------------------------------------------------------------------
// Blocked selective scan, phase 3.
// ---------------------------------------------------------------------------
__global__ __launch_bounds__(256) void scan_chunk2(
    float* __restrict__ dty, const float* __restrict__ u,
    const float* __restrict__ dbc, const float* __restrict__ xz,
    const float* __restrict__ A_log, const float* __restrict__ Dv,
    const float* __restrict__ hin) {
  int g = blockIdx.x * 256 + threadIdx.x;
  if (g >= BATCH * NC * D_INNER) return;
  int d = g % D_INNER;
  int c = (g / D_INNER) % NC;
  int b = g / (D_INNER * NC);
  float A[D_STATE];
#pragma unroll
  for (int s = 0; s < D_STATE; ++s) A[s] = -__expf(A_log[d * D_STATE + s]);
  float Dval = Dv[d];
  float h[D_STATE];
  size_t hbase = (((size_t)b * NC + c) * D_STATE) * D_INNER + d;
#pragma unroll
  for (int s = 0; s < D_STATE; ++s) h[s] = hin[hbase + (size_t)s * D_INNER];
  int t0 = c * CHUNK_T;
  for (int t = t0; t < t0 + CHUNK_T; ++t) {
    size_t rowb = (size_t)b * SEQLEN + t;
    float dtv = dty[rowb * D_INNER + d];
    float uv  = u[rowb * D_INNER + d];
    const float* bc = dbc + rowb * DBC_W;
    float dtu = dtv * uv;
    float yv = 0.f;
#pragma unroll
    for (int s = 0; s < D_STATE; ++s) {
      float da = __expf(dtv * A[s]);
      h[s] = da * h[s] + dtu * bc[DT_RANK + s];
      yv += h[s] * bc[DT_RANK + D_STATE + s];
    }
    float zv = xz[rowb * (2 * D_INNER) + D_INNER + d];
    float sig = 1.f / (1.f + __expf(-zv));
    float yo = (yv + uv * Dval) * (zv * sig);
    dty[rowb * D_INNER + d] = yo;
  }
}

// ---------------------------------------------------------------------------
// Final: residual add + LN(normf) + LN(dec), last rtn tokens only.
// ---------------------------------------------------------------------------
__global__ __launch_bounds__(256) void final_kernel(
    const float* __restrict__ hh, const float* __restrict__ resid,
    const float* __restrict__ fw, const float* __restrict__ fb,
    const float* __restrict__ dw, const float* __restrict__ db,
    float* __restrict__ out, int rtn) {
  int rowo = blockIdx.x;                 // 0 .. BATCH*rtn-1
  int b = rowo / rtn;
  int t = SEQLEN - rtn + (rowo % rtn);
  int tid = threadIdx.x;
  size_t base = ((size_t)b * SEQLEN + t) * D_MODEL;
  __shared__ float red[256];
  __shared__ float s_mu1, s_rs1, s_mu2, s_rs2;
  float v[3];
#pragma unroll
  for (int i = 0; i < 3; ++i) {
    int c = tid + i * 256;
    v[i] = hh[base + c] + resid[base + c];
  }
  // --- LN 1 ---
  red[tid] = v[0] + v[1] + v[2]; __syncthreads();
  for (int off = 128; off > 0; off >>= 1) {
    if (tid < off) red[tid] += red[tid + off];
    __syncthreads();
  }
  if (tid == 0) s_mu1 = red[0] / D_MODEL;
  __syncthreads();
  float mu = s_mu1, q = 0.f;
#pragma unroll
  for (int i = 0; i < 3; ++i) { float dd = v[i] - mu; q += dd * dd; }
  __syncthreads();
  red[tid] = q; __syncthreads();
  for (int off = 128; off > 0; off >>= 1) {
    if (tid < off) red[tid] += red[tid + off];
    __syncthreads();
  }
  if (tid == 0) s_rs1 = rsqrtf(red[0] / D_MODEL + 1e-5f);
  __syncthreads();
  float rs = s_rs1;
#pragma unroll
  for (int i = 0; i < 3; ++i) {
    int c = tid + i * 256;
    v[i] = (v[i] - mu) * rs * fw[c] + fb[c];
  }
  // --- LN 2 ---
  __syncthreads();
  red[tid] = v[0] + v[1] + v[2]; __syncthreads();
  for (int off = 128; off > 0; off >>= 1) {
    if (tid < off) red[tid] += red[tid + off];
    __syncthreads();
  }
  if (tid == 0) s_mu2 = red[0] / D_MODEL;
  __syncthreads();
  mu = s_mu2; q = 0.f;
#pragma unroll
  for (int i = 0; i < 3; ++i) { float dd = v[i] - mu; q += dd * dd; }
  __syncthreads();
  red[tid] = q; __syncthreads();
  for (int off = 128; off > 0; off >>= 1) {
    if (tid < off) red[tid] += red[tid + off];
    __syncthreads();
  }
  if (tid == 0) s_rs2 = rsqrtf(red[0] / D_MODEL + 1e-5f);
  __syncthreads();
  rs = s_rs2;
#pragma unroll
  for (int i = 0; i < 3; ++i) {
    int c = tid + i * 256;
    out[(size_t)rowo * D_MODEL + c] = (v[i] - mu) * rs * dw[c] + db[c];
  }
}

// ---------------------------------------------------------------------------
extern "C" void kernel_launch(void* const* d_in, const int* in_sizes, int n_in,
                              void* d_out, int out_size, void* d_ws, size_t ws_size,
                              hipStream_t stream) {
  const float* x       = (const float*)d_in[0];
  const float* pos     = (const float*)d_in[1];
  const float* norm_w  = (const float*)d_in[2];
  const float* norm_b  = (const float*)d_in[3];
  const float* in_proj = (const float*)d_in[4];
  const float* conv_w  = (const float*)d_in[5];
  const float* conv_b  = (const float*)d_in[6];
  const float* x_proj  = (const float*)d_in[7];
  const float* dt_w    = (const float*)d_in[8];
  const float* dt_b    = (const float*)d_in[9];
  const float* A_log   = (const float*)d_in[10];
  const float* Dv      = (const float*)d_in[11];
  const float* out_proj= (const float*)d_in[12];
  const float* normf_w = (const float*)d_in[13];
  const float* normf_b = (const float*)d_in[14];
  const float* dec_w   = (const float*)d_in[15];
  const float* dec_b   = (const float*)d_in[16];
  int rtn = out_size / (BATCH * D_MODEL);   // return_token_num

  float* ws    = (float*)d_ws;
  float* resid = ws;                                 // NTOK*D_MODEL
  float* hh    = resid + (size_t)NTOK * D_MODEL;     // NTOK*D_MODEL (h / hidden)
  float* xz    = hh    + (size_t)NTOK * D_MODEL;     // NTOK*2*D_INNER
  float* u     = xz    + (size_t)NTOK * 2 * D_INNER; // NTOK*D_INNER
  float* dbc   = u     + (size_t)NTOK * D_INNER;     // NTOK*80
  float* dty   = dbc   + (size_t)NTOK * DBC_W;       // NTOK*D_INNER (dt then y)
  float* Sbuf  = dty   + (size_t)NTOK * D_INNER;     // BATCH*NC*D_STATE*D_INNER
  float* dtsum = Sbuf  + (size_t)BATCH * NC * D_STATE * D_INNER; // BATCH*NC*D_INNER

  for (int l = 0; l < N_LAYER; ++l) {
    ln_kernel<<<NTOK, 256, 0, stream>>>(x, pos, resid, hh,
        norm_w + l * D_MODEL, norm_b + l * D_MODEL, l == 0);

    dim3 g1(2 * D_INNER / 128, NTOK / 128);
    gemm_abt<<<g1, 256, 0, stream>>>(hh,
        in_proj + (size_t)l * 2 * D_INNER * D_MODEL, xz,
        NTOK, 2 * D_INNER, D_MODEL);

    conv_silu_kernel<<<(NTOK * D_INNER + 255) / 256, 256, 0, stream>>>(
        xz, conv_w + (size_t)l * D_INNER * D_CONV, conv_b + l * D_INNER, u);

    xproj_kernel<<<(NTOK * DBC_W + 255) / 256, 256, 0, stream>>>(
        u, x_proj + (size_t)l * DBC_W * D_INNER, dbc);

    dt_kernel<<<(NTOK * D_INNER + 255) / 256, 256, 0, stream>>>(
        dbc, dt_w + (size_t)l * D_INNER * DT_RANK, dt_b + l * D_INNER, dty);

    const float* Al = A_log + (size_t)l * D_INNER * D_STATE;
    int tot1 = BATCH * NC * D_INNER;
    scan_chunk1<<<(tot1 + 255) / 256, 256, 0, stream>>>(
        dty, u, dbc, Al, Sbuf, dtsum);
    scan_combine<<<(BATCH * D_INNER + 255) / 256, 256, 0, stream>>>(
        Sbuf, dtsum, Al);
    scan_chunk2<<<(tot1 + 255) / 256, 256, 0, stream>>>(
        dty, u, dbc, xz, Al, Dv + l * D_INNER, Sbuf);

    dim3 g2(D_MODEL / 128, NTOK / 128);
    gemm_abt<<<g2, 256, 0, stream>>>(dty,
        out_proj + (size_t)l * D_MODEL * D_INNER, hh,
        NTOK, D_MODEL, D_INNER);
  }

  final_kernel<<<BATCH * rtn, 256, 0, stream>>>(
      hh, resid, normf_w, normf_b, dec_w, dec_b, (float*)d_out, rtn);
}

// Round 3
// 6235.223 us; speedup vs baseline: 3.0312x; 1.2341x over previous
//
#include <hip/hip_runtime.h>
#include <math.h>

#define D_MODEL 768
#define N_LAYER 8
#define D_INNER 1536
#define D_STATE 16
#define DT_RANK 48
#define D_CONV  4
#define BATCH   4
#define SEQLEN  1024
#define NTOK    (BATCH*SEQLEN)      // 4096 token rows
#define DBC_W   (DT_RANK + 2*D_STATE)  // 80
#define NC      32                  // scan chunks per sequence
#define CHUNK_T (SEQLEN/NC)         // 32 timesteps per chunk

// ---------------------------------------------------------------------------
// LayerNorm + residual update.  One block per token row (768 elems, 256 thr).
// ---------------------------------------------------------------------------
__global__ __launch_bounds__(256) void ln_kernel(
    const float* __restrict__ x, const float* __restrict__ pos,
    float* __restrict__ resid, float* __restrict__ hh,
    const float* __restrict__ w, const float* __restrict__ b, int first) {
  int row = blockIdx.x;
  int tid = threadIdx.x;
  int base = row * D_MODEL;
  __shared__ float red[256];
  __shared__ float s_mu, s_rs;
  float v[3];
#pragma unroll
  for (int i = 0; i < 3; ++i) {
    int c = tid + i * 256;
    float r;
    if (first) r = x[base + c] + pos[base + c];
    else       r = resid[base + c] + hh[base + c];
    resid[base + c] = r;
    v[i] = r;
  }
  float s = v[0] + v[1] + v[2];
  red[tid] = s; __syncthreads();
  for (int off = 128; off > 0; off >>= 1) {
    if (tid < off) red[tid] += red[tid + off];
    __syncthreads();
  }
  if (tid == 0) s_mu = red[0] / D_MODEL;
  __syncthreads();
  float mu = s_mu;
  float q = 0.f;
#pragma unroll
  for (int i = 0; i < 3; ++i) { float d = v[i] - mu; q += d * d; }
  __syncthreads();
  red[tid] = q; __syncthreads();
  for (int off = 128; off > 0; off >>= 1) {
    if (tid < off) red[tid] += red[tid + off];
    __syncthreads();
  }
  if (tid == 0) s_rs = rsqrtf(red[0] / D_MODEL + 1e-5f);
  __syncthreads();
  float rs = s_rs;
#pragma unroll
  for (int i = 0; i < 3; ++i) {
    int c = tid + i * 256;
    hh[base + c] = (v[i] - mu) * rs * w[c] + b[c];
  }
}

// ---------------------------------------------------------------------------
// C[M x N] = A[M x K] * B[N x K]^T   (row-major, fp32, leading dims lda/ldb)
// BM=BN=128, BK=16, 256 threads, 8x8 micro-tile per thread in split form.
// Requires M%128==0, N%128==0, K%16==0, lda/ldb multiples of 4.
// ---------------------------------------------------------------------------
__global__ __launch_bounds__(256) void gemm_abt(
    const float* __restrict__ A, int lda, const float* __restrict__ B, int ldb,
    float* __restrict__ C, int M, int N, int K) {
  const int BM = 128, BN = 128, BK = 16;
  __shared__ __align__(16) float As[BK][BM + 4];
  __shared__ __align__(16) float Bs[BK][BN + 4];
  int brow = blockIdx.y * BM;
  int bcol = blockIdx.x * BN;
  int tid = threadIdx.x;
  int tr = (tid / 16) * 4;   // 0..60
  int tc = (tid % 16) * 4;   // 0..60
  float acc[2][2][4][4] = {};   // [row-half][col-half][i][j]
  for (int k0 = 0; k0 < K; k0 += BK) {
#pragma unroll
    for (int it = 0; it < 2; ++it) {
      int idx = tid + it * 256;          // 0..511
      int r  = idx >> 2;                 // 0..127
      int cq = (idx & 3) * 4;            // 0,4,8,12
      float4 a = *(const float4*)&A[(size_t)(brow + r) * lda + k0 + cq];
      As[cq + 0][r] = a.x; As[cq + 1][r] = a.y;
      As[cq + 2][r] = a.z; As[cq + 3][r] = a.w;
      float4 b = *(const float4*)&B[(size_t)(bcol + r) * ldb + k0 + cq];
      Bs[cq + 0][r] = b.x; Bs[cq + 1][r] = b.y;
      Bs[cq + 2][r] = b.z; Bs[cq + 3][r] = b.w;
    }
    __syncthreads();
#pragma unroll
    for (int kk = 0; kk < BK; ++kk) {
      float4 a0 = *(const float4*)&As[kk][tr];
      float4 a1 = *(const float4*)&As[kk][tr + 64];
      float4 b0 = *(const float4*)&Bs[kk][tc];
      float4 b1 = *(const float4*)&Bs[kk][tc + 64];
      float ar[2][4] = {{a0.x, a0.y, a0.z, a0.w}, {a1.x, a1.y, a1.z, a1.w}};
      float br[2][4] = {{b0.x, b0.y, b0.z, b0.w}, {b1.x, b1.y, b1.z, b1.w}};
#pragma unroll
      for (int rh = 0; rh < 2; ++rh)
#pragma unroll
        for (int ch = 0; ch < 2; ++ch)
#pragma unroll
          for (int i = 0; i < 4; ++i)
#pragma unroll
            for (int j = 0; j < 4; ++j)
              acc[rh][ch][i][j] += ar[rh][i] * br[ch][j];
    }
    __syncthreads();
  }
#pragma unroll
  for (int rh = 0; rh < 2; ++rh)
#pragma unroll
    for (int i = 0; i < 4; ++i) {
      int row = brow + tr + rh * 64 + i;
#pragma unroll
      for (int ch = 0; ch < 2; ++ch) {
        float4 o = make_float4(acc[rh][ch][i][0], acc[rh][ch][i][1],
                               acc[rh][ch][i][2], acc[rh][ch][i][3]);
        *(float4*)&C[(size_t)row * N + bcol + tc + ch * 64] = o;
      }
    }
}

// ---------------------------------------------------------------------------
// dbc[M=4096][80] = u[4096][1536] . xp[80][1536]^T   (skinny GEMM)
// One block per 64 rows, all 80 cols.  BK=64.  4x5 micro-tile per thread.
// LDS strides 65/81 chosen conflict-free for both staging writes and reads.
// ---------------------------------------------------------------------------
__global__ __launch_bounds__(256) void xproj_gemm(
    const float* __restrict__ u, const float* __restrict__ xp,
    float* __restrict__ dbc) {
  const int BM = 64, BK = 64;
  __shared__ float As[BK][BM + 1];     // stride 65
  __shared__ float Bs[BK][DBC_W + 1];  // stride 81
  int brow = blockIdx.x * BM;
  int tid = threadIdx.x;
  int tr = (tid / 16) * 4;    // 0..60
  int tc = (tid % 16) * 5;    // 0..75
  float acc[4][5] = {};
  for (int k0 = 0; k0 < D_INNER; k0 += BK) {
#pragma unroll
    for (int it = 0; it < 4; ++it) {           // A: 64 rows x 64 k
      int lin = tid + it * 256;                // 0..1023
      int r  = lin >> 4;                       // 0..63
      int kq = (lin & 15) * 4;
      float4 a = *(const float4*)&u[(size_t)(brow + r) * D_INNER + k0 + kq];
      As[kq + 0][r] = a.x; As[kq + 1][r] = a.y;
      As[kq + 2][r] = a.z; As[kq + 3][r] = a.w;
    }
#pragma unroll
    for (int it = 0; it < 5; ++it) {           // B: 80 rows x 64 k
      int lin = tid + it * 256;                // 0..1279
      int e  = lin >> 4;                       // 0..79
      int kq = (lin & 15) * 4;
      float4 b = *(const float4*)&xp[(size_t)e * D_INNER + k0 + kq];
      Bs[kq + 0][e] = b.x; Bs[kq + 1][e] = b.y;
      Bs[kq + 2][e] = b.z; Bs[kq + 3][e] = b.w;
    }
    __syncthreads();
#pragma unroll
    for (int kk = 0; kk < BK; ++kk) {
      float ar[4], br[5];
#pragma unroll
      for (int i = 0; i < 4; ++i) ar[i] = As[kk][tr + i];
#pragma unroll
      for (int j = 0; j < 5; ++j) br[j] = Bs[kk][tc + j];
#pragma unroll
      for (int i = 0; i < 4; ++i)
#pragma unroll
        for (int j = 0; j < 5; ++j) acc[i][j] += ar[i] * br[j];
    }
    __syncthreads();
  }
#pragma unroll
  for (int i = 0; i < 4; ++i)
#pragma unroll
    for (int j = 0; j < 5; ++j)
      dbc[(size_t)(brow + tr + i) * DBC_W + tc + j] = acc[i][j];
}

// ---------------------------------------------------------------------------
// Causal depthwise conv (width 4) + bias + SiLU.  xm = xz[..., :D_INNER].
// ---------------------------------------------------------------------------
__global__ __launch_bounds__(256) void conv_silu_kernel(
    const float* __restrict__ xz, const float* __restrict__ cw,
    const float* __restrict__ cb, float* __restrict__ u) {
  int idx = blockIdx.x * 256 + threadIdx.x;
  if (idx >= NTOK * D_INNER) return;
  int c = idx % D_INNER;
  int t = (idx / D_INNER) % SEQLEN;
  int b = idx / (D_INNER * SEQLEN);
  float acc = cb[c];
#pragma unroll
  for (int k = 0; k < D_CONV; ++k) {
    int tt = t + k - (D_CONV - 1);
    if (tt >= 0)
      acc += xz[(size_t)(b * SEQLEN + tt) * (2 * D_INNER) + c] * cw[c * D_CONV + k];
  }
  float sig = 1.f / (1.f + __expf(-acc));
  u[idx] = acc * sig;
}

__device__ __forceinline__ float softplusf(float a) {
  return (a > 20.f) ? a : log1pf(__expf(a));
}

// ---------------------------------------------------------------------------
// Blocked selective scan, phase 1.  dty holds RAW dt scores (pre-bias,
// pre-softplus); bias+softplus applied here on the fly.
// ---------------------------------------------------------------------------
__global__ __launch_bounds__(256) void scan_chunk1(
    const float* __restrict__ dty, const float* __restrict__ u,
    const float* __restrict__ dbc, const float* __restrict__ A_log,
    const float* __restrict__ dtb,
    float* __restrict__ S, float* __restrict__ dtsum) {
  int g = blockIdx.x * 256 + threadIdx.x;
  if (g >= BATCH * NC * D_INNER) return;
  int d = g % D_INNER;
  int c = (g / D_INNER) % NC;
  int b = g / (D_INNER * NC);
  float A[D_STATE];
#pragma unroll
  for (int s = 0; s < D_STATE; ++s) A[s] = -__expf(A_log[d * D_STATE + s]);
  float bias = dtb[d];
  float h[D_STATE];
#pragma unroll
  for (int s = 0; s < D_STATE; ++s) h[s] = 0.f;
  float dts = 0.f;
  int t0 = c * CHUNK_T;
  for (int t = t0; t < t0 + CHUNK_T; ++t) {
    size_t rowb = (size_t)b * SEQLEN + t;
    float dtv = softplusf(dty[rowb * D_INNER + d] + bias);
    float uv  = u[rowb * D_INNER + d];
    const float* bc = dbc + rowb * DBC_W;
    float dtu = dtv * uv;
    dts += dtv;
#pragma unroll
    for (int s = 0; s < D_STATE; ++s) {
      float da = __expf(dtv * A[s]);
      h[s] = da * h[s] + dtu * bc[DT_RANK + s];
    }
  }
  size_t base = (((size_t)b * NC + c) * D_STATE) * D_INNER + d;
#pragma unroll
  for (int s = 0; s < D_STATE; ++s) S[base + (size_t)s * D_INNER] = h[s];
  dtsum[((size_t)b * NC + c) * D_INNER + d] = dts;
}

// ---------------------------------------------------------------------------
// Blocked selective scan, phase 2 (serial chunk combine, tiny).
// ---------------------------------------------------------------------------
__global__ __launch_bounds__(256) void scan_combine(
    float* __restrict__ S, const float* __restrict__ dtsum,
    const float* __restrict__ A_log) {
  int g = blockIdx.x * 256 + threadIdx.x;
  if (g >= BATCH * D_INNER) return;
  int b = g / D_INNER, d = g % D_INNER;
  float A[D_STATE];
#pragma unroll
  for (int s = 0; s < D_STATE; ++s) A[s] = -__expf(A_log[d * D_STATE + s]);
  float h[D_STATE];
#pragma unroll
  for (int s = 0; s < D_STATE; ++s) h[s] = 0.f;
  for (int c = 0; c < NC; ++c) {
    size_t base = (((size_t)b * NC + c) * D_STATE) * D_INNER + d;
    float dts = dtsum[((size_t)b * NC + c) * D_INNER + d];
#pragma unroll
    for (int s = 0; s < D_STATE; ++s) {
      size_t off = base + (size_t)s * D_INNER;
      float Sv = S[off];
      S[off] = h[s];                       // h_in for chunk c
      h[s] = __expf(dts * A[s]) * h[s] + Sv;
    }
  }
}

// ---------------------------------------------------------------------------
// Blocked selective scan, phase 3.  Applies bias+softplus to raw dt,
// computes y, D-skip, SiLU(z) gating; writes gated y over dty.
// ---------------------------------------------------------------------------
__global__ __launch_bounds__(256) void scan_chunk2(
    float* __restrict__ dty, const float* __restrict__ u,
    const float* __restrict__ dbc, const float* __restrict__ xz,
    const float* __restrict__ A_log, const float* __restrict__ dtb,
    const float* __restrict__ Dv, const float* __restrict__ hin) {
  int g = blockIdx.x * 256 + threadIdx.x;
  if (g >= BATCH * NC * D_INNER) return;
  int d = g % D_INNER;
  int c = (g / D_INNER) % NC;
  int b = g / (D_INNER * NC);
  float A[D_STATE];
#pragma unroll
  for (int s = 0; s < D_STATE; ++s) A[s] = -__expf(A_log[d * D_STATE + s]);
  float bias = dtb[d];
  float Dval = Dv[d];
  float h[D_STATE];
  size_t hbase = (((size_t)b * NC + c) * D_STATE) * D_INNER + d;
#pragma unroll
  for (int s = 0; s < D_STATE; ++s) h[s] = hin[hbase + (size_t)s * D_INNER];
  int t0 = c * CHUNK_T;
  for (int t = t0; t < t0 + CHUNK_T; ++t) {
    size_t rowb = (size_t)b * SEQLEN + t;
    float dtv = softplusf(dty[rowb * D_INNER + d] + bias);
    float uv  = u[rowb * D_INNER + d];
    const float* bc = dbc + rowb * DBC_W;
    float dtu = dtv * uv;
    float yv = 0.f;
#pragma unroll
    for (int s = 0; s < D_STATE; ++s) {
      float da = __expf(dtv * A[s]);
      h[s] = da * h[s] + dtu * bc[DT_RANK + s];
      yv += h[s] * bc[DT_RANK + D_STATE + s];
    }
    float zv = xz[rowb * (2 * D_INNER) + D_INNER + d];
    float sig = 1.f / (1.f + __expf(-zv));
    float yo = (yv + uv * Dval) * (zv * sig);
    dty[rowb * D_INNER + d] = yo;
  }
}

// ---------------------------------------------------------------------------
// Final: residual add + LN(normf) + LN(dec), last rtn tokens only.
// ---------------------------------------------------------------------------
__global__ __launch_bounds__(256) void final_kernel(
    const float* __restrict__ hh, const float* __restrict__ resid,
    const float* __restrict__ fw, const float* __restrict__ fb,
    const float* __restrict__ dw, const float* __restrict__ db,
    float* __restrict__ out, int rtn) {
  int rowo = blockIdx.x;                 // 0 .. BATCH*rtn-1
  int b = rowo / rtn;
  int t = SEQLEN - rtn + (rowo % rtn);
  int tid = threadIdx.x;
  size_t base = ((size_t)b * SEQLEN + t) * D_MODEL;
  __shared__ float red[256];
  __shared__ float s_mu1, s_rs1, s_mu2, s_rs2;
  float v[3];
#pragma unroll
  for (int i = 0; i < 3; ++i) {
    int c = tid + i * 256;
    v[i] = hh[base + c] + resid[base + c];
  }
  // --- LN 1 ---
  red[tid] = v[0] + v[1] + v[2]; __syncthreads();
  for (int off = 128; off > 0; off >>= 1) {
    if (tid < off) red[tid] += red[tid + off];
    __syncthreads();
  }
  if (tid == 0) s_mu1 = red[0] / D_MODEL;
  __syncthreads();
  float mu = s_mu1, q = 0.f;
#pragma unroll
  for (int i = 0; i < 3; ++i) { float dd = v[i] - mu; q += dd * dd; }
  __syncthreads();
  red[tid] = q; __syncthreads();
  for (int off = 128; off > 0; off >>= 1) {
    if (tid < off) red[tid] += red[tid + off];
    __syncthreads();
  }
  if (tid == 0) s_rs1 = rsqrtf(red[0] / D_MODEL + 1e-5f);
  __syncthreads();
  float rs = s_rs1;
#pragma unroll
  for (int i = 0; i < 3; ++i) {
    int c = tid + i * 256;
    v[i] = (v[i] - mu) * rs * fw[c] + fb[c];
  }
  // --- LN 2 ---
  __syncthreads();
  red[tid] = v[0] + v[1] + v[2]; __syncthreads();
  for (int off = 128; off > 0; off >>= 1) {
    if (tid < off) red[tid] += red[tid + off];
    __syncthreads();
  }
  if (tid == 0) s_mu2 = red[0] / D_MODEL;
  __syncthreads();
  mu = s_mu2; q = 0.f;
#pragma unroll
  for (int i = 0; i < 3; ++i) { float dd = v[i] - mu; q += dd * dd; }
  __syncthreads();
  red[tid] = q; __syncthreads();
  for (int off = 128; off > 0; off >>= 1) {
    if (tid < off) red[tid] += red[tid + off];
    __syncthreads();
  }
  if (tid == 0) s_rs2 = rsqrtf(red[0] / D_MODEL + 1e-5f);
  __syncthreads();
  rs = s_rs2;
#pragma unroll
  for (int i = 0; i < 3; ++i) {
    int c = tid + i * 256;
    out[(size_t)rowo * D_MODEL + c] = (v[i] - mu) * rs * dw[c] + db[c];
  }
}

// ---------------------------------------------------------------------------
extern "C" void kernel_launch(void* const* d_in, const int* in_sizes, int n_in,
                              void* d_out, int out_size, void* d_ws, size_t ws_size,
                              hipStream_t stream) {
  const float* x       = (const float*)d_in[0];
  const float* pos     = (const float*)d_in[1];
  const float* norm_w  = (const float*)d_in[2];
  const float* norm_b  = (const float*)d_in[3];
  const float* in_proj = (const float*)d_in[4];
  const float* conv_w  = (const float*)d_in[5];
  const float* conv_b  = (const float*)d_in[6];
  const float* x_proj  = (const float*)d_in[7];
  const float* dt_w    = (const float*)d_in[8];
  const float* dt_b    = (const float*)d_in[9];
  const float* A_log   = (const float*)d_in[10];
  const float* Dv      = (const float*)d_in[11];
  const float* out_proj= (const float*)d_in[12];
  const float* normf_w = (const float*)d_in[13];
  const float* normf_b = (const float*)d_in[14];
  const float* dec_w   = (const float*)d_in[15];
  const float* dec_b   = (const float*)d_in[16];
  int rtn = out_size / (BATCH * D_MODEL);   // return_token_num

  float* ws    = (float*)d_ws;
  float* resid = ws;                                 // NTOK*D_MODEL
  float* hh    = resid + (size_t)NTOK * D_MODEL;     // NTOK*D_MODEL (h / hidden)
  float* xz    = hh    + (size_t)NTOK * D_MODEL;     // NTOK*2*D_INNER
  float* u     = xz    + (size_t)NTOK * 2 * D_INNER; // NTOK*D_INNER
  float* dbc   = u     + (size_t)NTOK * D_INNER;     // NTOK*80
  float* dty   = dbc   + (size_t)NTOK * DBC_W;       // NTOK*D_INNER (dt then y)
  float* Sbuf  = dty   + (size_t)NTOK * D_INNER;     // BATCH*NC*D_STATE*D_INNER
  float* dtsum = Sbuf  + (size_t)BATCH * NC * D_STATE * D_INNER; // BATCH*NC*D_INNER

  for (int l = 0; l < N_LAYER; ++l) {
    ln_kernel<<<NTOK, 256, 0, stream>>>(x, pos, resid, hh,
        norm_w + l * D_MODEL, norm_b + l * D_MODEL, l == 0);

    dim3 g1(2 * D_INNER / 128, NTOK / 128);
    gemm_abt<<<g1, 256, 0, stream>>>(hh, D_MODEL,
        in_proj + (size_t)l * 2 * D_INNER * D_MODEL, D_MODEL, xz,
        NTOK, 2 * D_INNER, D_MODEL);

    conv_silu_kernel<<<(NTOK * D_INNER + 255) / 256, 256, 0, stream>>>(
        xz, conv_w + (size_t)l * D_INNER * D_CONV, conv_b + l * D_INNER, u);

    xproj_gemm<<<NTOK / 64, 256, 0, stream>>>(
        u, x_proj + (size_t)l * DBC_W * D_INNER, dbc);

    // dt raw scores: dbc[:, :48] @ dt_w^T  -> dty   (M=4096, N=1536, K=48)
    dim3 gdt(D_INNER / 128, NTOK / 128);
    gemm_abt<<<gdt, 256, 0, stream>>>(dbc, DBC_W,
        dt_w + (size_t)l * D_INNER * DT_RANK, DT_RANK, dty,
        NTOK, D_INNER, DT_RANK);

    const float* Al = A_log + (size_t)l * D_INNER * D_STATE;
    const float* dtbl = dt_b + (size_t)l * D_INNER;
    int tot1 = BATCH * NC * D_INNER;
    scan_chunk1<<<(tot1 + 255) / 256, 256, 0, stream>>>(
        dty, u, dbc, Al, dtbl, Sbuf, dtsum);
    scan_combine<<<(BATCH * D_INNER + 255) / 256, 256, 0, stream>>>(
        Sbuf, dtsum, Al);
    scan_chunk2<<<(tot1 + 255) / 256, 256, 0, stream>>>(
        dty, u, dbc, xz, Al, dtbl, Dv + l * D_INNER, Sbuf);

    dim3 g2(D_MODEL / 128, NTOK / 128);
    gemm_abt<<<g2, 256, 0, stream>>>(dty, D_INNER,
        out_proj + (size_t)l * D_MODEL * D_INNER, D_INNER, hh,
        NTOK, D_MODEL, D_INNER);
  }

  final_kernel<<<BATCH * rtn, 256, 0, stream>>>(
      hh, resid, normf_w, normf_b, dec_w, dec_b, (float*)d_out, rtn);
}

// Round 4
// 4311.713 us; speedup vs baseline: 4.3835x; 1.4461x over previous
//
#include <hip/hip_runtime.h>
#include <math.h>

#define D_MODEL 768
#define N_LAYER 8
#define D_INNER 1536
#define D_STATE 16
#define DT_RANK 48
#define D_CONV  4
#define BATCH   4
#define SEQLEN  1024
#define NTOK    (BATCH*SEQLEN)      // 4096 token rows
#define DBC_W   (DT_RANK + 2*D_STATE)  // 80
#define NC      32                  // scan chunks per sequence
#define CHUNK_T (SEQLEN/NC)         // 32 timesteps per chunk

typedef __attribute__((ext_vector_type(8))) short short8v;   // 8 bf16 (4 VGPRs)
typedef __attribute__((ext_vector_type(4))) float float4v;   // 4 fp32 acc

// Split fp32 into hi+lo bf16 (both RNE).  x ~= hi + lo, |err| ~ 2^-17 |x|.
__device__ __forceinline__ void split_bf16(float x, short& hi, short& lo) {
  unsigned u = __float_as_uint(x);
  unsigned r = (u + 0x7fffu + ((u >> 16) & 1u)) >> 16;
  hi = (short)r;
  float fhi = __uint_as_float(r << 16);
  float xl = x - fhi;
  unsigned u2 = __float_as_uint(xl);
  unsigned r2 = (u2 + 0x7fffu + ((u2 >> 16) & 1u)) >> 16;
  lo = (short)r2;
}

// ---------------------------------------------------------------------------
// Weight split: fp32 [n] -> bf16 hi[n], lo[n].  n4 = n/4, float4-vectorized.
// ---------------------------------------------------------------------------
__global__ __launch_bounds__(256) void split_kernel(
    const float* __restrict__ src, short* __restrict__ hi,
    short* __restrict__ lo, int n4) {
  int stride = gridDim.x * 256;
  for (int i = blockIdx.x * 256 + threadIdx.x; i < n4; i += stride) {
    float4 v = ((const float4*)src)[i];
    short4 h, g;
    split_bf16(v.x, h.x, g.x);
    split_bf16(v.y, h.y, g.y);
    split_bf16(v.z, h.z, g.z);
    split_bf16(v.w, h.w, g.w);
    ((short4*)hi)[i] = h;
    ((short4*)lo)[i] = g;
  }
}

// ---------------------------------------------------------------------------
// LayerNorm + residual update.  One block per token row (768 elems, 256 thr).
// first=1: resid = x + pos.  first=0: resid += hy (prev out_proj output).
// Writes normalized output as split bf16 (hh_hi/hh_lo) for the MFMA GEMM.
// ---------------------------------------------------------------------------
__global__ __launch_bounds__(256) void ln_kernel(
    const float* __restrict__ x, const float* __restrict__ pos,
    float* __restrict__ resid, const float* __restrict__ hy,
    short* __restrict__ hh_hi, short* __restrict__ hh_lo,
    const float* __restrict__ w, const float* __restrict__ b, int first) {
  int row = blockIdx.x;
  int tid = threadIdx.x;
  int base = row * D_MODEL;
  __shared__ float red[256];
  __shared__ float s_mu, s_rs;
  float v[3];
#pragma unroll
  for (int i = 0; i < 3; ++i) {
    int c = tid + i * 256;
    float r;
    if (first) r = x[base + c] + pos[base + c];
    else       r = resid[base + c] + hy[base + c];
    resid[base + c] = r;
    v[i] = r;
  }
  float s = v[0] + v[1] + v[2];
  red[tid] = s; __syncthreads();
  for (int off = 128; off > 0; off >>= 1) {
    if (tid < off) red[tid] += red[tid + off];
    __syncthreads();
  }
  if (tid == 0) s_mu = red[0] / D_MODEL;
  __syncthreads();
  float mu = s_mu;
  float q = 0.f;
#pragma unroll
  for (int i = 0; i < 3; ++i) { float d = v[i] - mu; q += d * d; }
  __syncthreads();
  red[tid] = q; __syncthreads();
  for (int off = 128; off > 0; off >>= 1) {
    if (tid < off) red[tid] += red[tid + off];
    __syncthreads();
  }
  if (tid == 0) s_rs = rsqrtf(red[0] / D_MODEL + 1e-5f);
  __syncthreads();
  float rs = s_rs;
#pragma unroll
  for (int i = 0; i < 3; ++i) {
    int c = tid + i * 256;
    float val = (v[i] - mu) * rs * w[c] + b[c];
    short hv, lv; split_bf16(val, hv, lv);
    hh_hi[base + c] = hv;
    hh_lo[base + c] = lv;
  }
}

// ---------------------------------------------------------------------------
// bf16x3 MFMA GEMM:  C[M][N] = A[M][K] . B[N][K]^T  (fp32-equivalent accuracy)
// A,B given as split bf16 (hi,lo).  Computes hi*hi + hi*lo + lo*hi.
// 128x128 tile, BK=32, 256 thr = 4 waves (2x2), 4x4 16x16x32 frags per wave.
// LDS rows stride 40 bf16 (80 B): 16B-aligned rows, conflict-free b128 reads.
// Requires M%128==0, N%128==0, K%32==0, lda/ldb multiples of 8.
// ---------------------------------------------------------------------------
__global__ __launch_bounds__(256) void gemm_bf16x3(
    const short* __restrict__ Ahi, const short* __restrict__ Alo, int lda,
    const short* __restrict__ Bhi, const short* __restrict__ Blo, int ldb,
    float* __restrict__ C, int M, int N, int K) {
  const int BK = 32, LDSS = 40;
  __shared__ short Ash[128][LDSS];
  __shared__ short Asl[128][LDSS];
  __shared__ short Bsh[128][LDSS];
  __shared__ short Bsl[128][LDSS];
  int brow = blockIdx.y * 128;
  int bcol = blockIdx.x * 128;
  int tid = threadIdx.x;
  int w = tid >> 6, l = tid & 63;
  int wr = (w >> 1) * 64;            // wave row origin in tile
  int wc = (w & 1) * 64;             // wave col origin in tile
  int lrow = l & 15;
  int lk = (l >> 4) * 8;             // k-offset of this lane's fragment
  float4v zero = {0.f, 0.f, 0.f, 0.f};
  float4v acc[4][4];
#pragma unroll
  for (int m = 0; m < 4; ++m)
#pragma unroll
    for (int n = 0; n < 4; ++n) acc[m][n] = zero;

  for (int k0 = 0; k0 < K; k0 += BK) {
#pragma unroll
    for (int it = 0; it < 2; ++it) {
      int idx = tid + it * 256;      // 0..511
      int r = idx >> 2;              // 0..127
      int q = (idx & 3) * 8;         // 0,8,16,24 (bf16 elems)
      *(uint4*)&Ash[r][q] = *(const uint4*)&Ahi[(size_t)(brow + r) * lda + k0 + q];
      *(uint4*)&Asl[r][q] = *(const uint4*)&Alo[(size_t)(brow + r) * lda + k0 + q];
      *(uint4*)&Bsh[r][q] = *(const uint4*)&Bhi[(size_t)(bcol + r) * ldb + k0 + q];
      *(uint4*)&Bsl[r][q] = *(const uint4*)&Blo[(size_t)(bcol + r) * ldb + k0 + q];
    }
    __syncthreads();
    short8v ah[4], al[4];
#pragma unroll
    for (int m = 0; m < 4; ++m) {
      ah[m] = *(const short8v*)&Ash[wr + m * 16 + lrow][lk];
      al[m] = *(const short8v*)&Asl[wr + m * 16 + lrow][lk];
    }
#pragma unroll
    for (int n = 0; n < 4; ++n) {
      short8v bh = *(const short8v*)&Bsh[wc + n * 16 + lrow][lk];
      short8v bl = *(const short8v*)&Bsl[wc + n * 16 + lrow][lk];
#pragma unroll
      for (int m = 0; m < 4; ++m) {
        acc[m][n] = __builtin_amdgcn_mfma_f32_16x16x32_bf16(ah[m], bh, acc[m][n], 0, 0, 0);
        acc[m][n] = __builtin_amdgcn_mfma_f32_16x16x32_bf16(ah[m], bl, acc[m][n], 0, 0, 0);
        acc[m][n] = __builtin_amdgcn_mfma_f32_16x16x32_bf16(al[m], bh, acc[m][n], 0, 0, 0);
      }
    }
    __syncthreads();
  }
  int drow = (l >> 4) * 4, dcol = l & 15;
#pragma unroll
  for (int m = 0; m < 4; ++m)
#pragma unroll
    for (int n = 0; n < 4; ++n)
#pragma unroll
      for (int j = 0; j < 4; ++j)
        C[(size_t)(brow + wr + m * 16 + drow + j) * N + bcol + wc + n * 16 + dcol] =
            acc[m][n][j];
}

// ---------------------------------------------------------------------------
// C[M x N] = A[M x K] * B[N x K]^T   (row-major, fp32, leading dims lda/ldb)
// Used only for the small dt projection (K=48).
// ---------------------------------------------------------------------------
__global__ __launch_bounds__(256) void gemm_abt(
    const float* __restrict__ A, int lda, const float* __restrict__ B, int ldb,
    float* __restrict__ C, int M, int N, int K) {
  const int BM = 128, BN = 128, BK = 16;
  __shared__ __align__(16) float As[BK][BM + 4];
  __shared__ __align__(16) float Bs[BK][BN + 4];
  int brow = blockIdx.y * BM;
  int bcol = blockIdx.x * BN;
  int tid = threadIdx.x;
  int tr = (tid / 16) * 4;   // 0..60
  int tc = (tid % 16) * 4;   // 0..60
  float acc[2][2][4][4] = {};   // [row-half][col-half][i][j]
  for (int k0 = 0; k0 < K; k0 += BK) {
#pragma unroll
    for (int it = 0; it < 2; ++it) {
      int idx = tid + it * 256;          // 0..511
      int r  = idx >> 2;                 // 0..127
      int cq = (idx & 3) * 4;            // 0,4,8,12
      float4 a = *(const float4*)&A[(size_t)(brow + r) * lda + k0 + cq];
      As[cq + 0][r] = a.x; As[cq + 1][r] = a.y;
      As[cq + 2][r] = a.z; As[cq + 3][r] = a.w;
      float4 b = *(const float4*)&B[(size_t)(bcol + r) * ldb + k0 + cq];
      Bs[cq + 0][r] = b.x; Bs[cq + 1][r] = b.y;
      Bs[cq + 2][r] = b.z; Bs[cq + 3][r] = b.w;
    }
    __syncthreads();
#pragma unroll
    for (int kk = 0; kk < BK; ++kk) {
      float4 a0 = *(const float4*)&As[kk][tr];
      float4 a1 = *(const float4*)&As[kk][tr + 64];
      float4 b0 = *(const float4*)&Bs[kk][tc];
      float4 b1 = *(const float4*)&Bs[kk][tc + 64];
      float ar[2][4] = {{a0.x, a0.y, a0.z, a0.w}, {a1.x, a1.y, a1.z, a1.w}};
      float br[2][4] = {{b0.x, b0.y, b0.z, b0.w}, {b1.x, b1.y, b1.z, b1.w}};
#pragma unroll
      for (int rh = 0; rh < 2; ++rh)
#pragma unroll
        for (int ch = 0; ch < 2; ++ch)
#pragma unroll
          for (int i = 0; i < 4; ++i)
#pragma unroll
            for (int j = 0; j < 4; ++j)
              acc[rh][ch][i][j] += ar[rh][i] * br[ch][j];
    }
    __syncthreads();
  }
#pragma unroll
  for (int rh = 0; rh < 2; ++rh)
#pragma unroll
    for (int i = 0; i < 4; ++i) {
      int row = brow + tr + rh * 64 + i;
#pragma unroll
      for (int ch = 0; ch < 2; ++ch) {
        float4 o = make_float4(acc[rh][ch][i][0], acc[rh][ch][i][1],
                               acc[rh][ch][i][2], acc[rh][ch][i][3]);
        *(float4*)&C[(size_t)row * N + bcol + tc + ch * 64] = o;
      }
    }
}

// ---------------------------------------------------------------------------
// dbc[M=4096][80] = u[4096][1536] . xp[80][1536]^T   (skinny GEMM, fp32)
// ---------------------------------------------------------------------------
__global__ __launch_bounds__(256) void xproj_gemm(
    const float* __restrict__ u, const float* __restrict__ xp,
    float* __restrict__ dbc) {
  const int BM = 64, BK = 64;
  __shared__ float As[BK][BM + 1];     // stride 65
  __shared__ float Bs[BK][DBC_W + 1];  // stride 81
  int brow = blockIdx.x * BM;
  int tid = threadIdx.x;
  int tr = (tid / 16) * 4;    // 0..60
  int tc = (tid % 16) * 5;    // 0..75
  float acc[4][5] = {};
  for (int k0 = 0; k0 < D_INNER; k0 += BK) {
#pragma unroll
    for (int it = 0; it < 4; ++it) {           // A: 64 rows x 64 k
      int lin = tid + it * 256;                // 0..1023
      int r  = lin >> 4;                       // 0..63
      int kq = (lin & 15) * 4;
      float4 a = *(const float4*)&u[(size_t)(brow + r) * D_INNER + k0 + kq];
      As[kq + 0][r] = a.x; As[kq + 1][r] = a.y;
      As[kq + 2][r] = a.z; As[kq + 3][r] = a.w;
    }
#pragma unroll
    for (int it = 0; it < 5; ++it) {           // B: 80 rows x 64 k
      int lin = tid + it * 256;                // 0..1279
      int e  = lin >> 4;                       // 0..79
      int kq = (lin & 15) * 4;
      float4 b = *(const float4*)&xp[(size_t)e * D_INNER + k0 + kq];
      Bs[kq + 0][e] = b.x; Bs[kq + 1][e] = b.y;
      Bs[kq + 2][e] = b.z; Bs[kq + 3][e] = b.w;
    }
    __syncthreads();
#pragma unroll
    for (int kk = 0; kk < BK; ++kk) {
      float ar[4], br[5];
#pragma unroll
      for (int i = 0; i < 4; ++i) ar[i] = As[kk][tr + i];
#pragma unroll
      for (int j = 0; j < 5; ++j) br[j] = Bs[kk][tc + j];
#pragma unroll
      for (int i = 0; i < 4; ++i)
#pragma unroll
        for (int j = 0; j < 5; ++j) acc[i][j] += ar[i] * br[j];
    }
    __syncthreads();
  }
#pragma unroll
  for (int i = 0; i < 4; ++i)
#pragma unroll
    for (int j = 0; j < 5; ++j)
      dbc[(size_t)(brow + tr + i) * DBC_W + tc + j] = acc[i][j];
}

// ---------------------------------------------------------------------------
// Causal depthwise conv (width 4) + bias + SiLU.  xm = xz[..., :D_INNER].
// ---------------------------------------------------------------------------
__global__ __launch_bounds__(256) void conv_silu_kernel(
    const float* __restrict__ xz, const float* __restrict__ cw,
    const float* __restrict__ cb, float* __restrict__ u) {
  int idx = blockIdx.x * 256 + threadIdx.x;
  if (idx >= NTOK * D_INNER) return;
  int c = idx % D_INNER;
  int t = (idx / D_INNER) % SEQLEN;
  int b = idx / (D_INNER * SEQLEN);
  float acc = cb[c];
#pragma unroll
  for (int k = 0; k < D_CONV; ++k) {
    int tt = t + k - (D_CONV - 1);
    if (tt >= 0)
      acc += xz[(size_t)(b * SEQLEN + tt) * (2 * D_INNER) + c] * cw[c * D_CONV + k];
  }
  float sig = 1.f / (1.f + __expf(-acc));
  u[idx] = acc * sig;
}

__device__ __forceinline__ float softplusf(float a) {
  return (a > 20.f) ? a : log1pf(__expf(a));
}

// ---------------------------------------------------------------------------
// Blocked selective scan, phase 1.  dty holds RAW dt scores (pre-bias,
// pre-softplus); bias+softplus applied here on the fly.
// ---------------------------------------------------------------------------
__global__ __launch_bounds__(256) void scan_chunk1(
    const float* __restrict__ dty, const float* __restrict__ u,
    const float* __restrict__ dbc, const float* __restrict__ A_log,
    const float* __restrict__ dtb,
    float* __restrict__ S, float* __restrict__ dtsum) {
  int g = blockIdx.x * 256 + threadIdx.x;
  if (g >= BATCH * NC * D_INNER) return;
  int d = g % D_INNER;
  int c = (g / D_INNER) % NC;
  int b = g / (D_INNER * NC);
  float A[D_STATE];
#pragma unroll
  for (int s = 0; s < D_STATE; ++s) A[s] = -__expf(A_log[d * D_STATE + s]);
  float bias = dtb[d];
  float h[D_STATE];
#pragma unroll
  for (int s = 0; s < D_STATE; ++s) h[s] = 0.f;
  float dts = 0.f;
  int t0 = c * CHUNK_T;
  for (int t = t0; t < t0 + CHUNK_T; ++t) {
    size_t rowb = (size_t)b * SEQLEN + t;
    float dtv = softplusf(dty[rowb * D_INNER + d] + bias);
    float uv  = u[rowb * D_INNER + d];
    const float* bc = dbc + rowb * DBC_W;
    float dtu = dtv * uv;
    dts += dtv;
#pragma unroll
    for (int s = 0; s < D_STATE; ++s) {
      float da = __expf(dtv * A[s]);
      h[s] = da * h[s] + dtu * bc[DT_RANK + s];
    }
  }
  size_t base = (((size_t)b * NC + c) * D_STATE) * D_INNER + d;
#pragma unroll
  for (int s = 0; s < D_STATE; ++s) S[base + (size_t)s * D_INNER] = h[s];
  dtsum[((size_t)b * NC + c) * D_INNER + d] = dts;
}

// ---------------------------------------------------------------------------
// Blocked selective scan, phase 2 (serial chunk combine, tiny).
// ---------------------------------------------------------------------------
__global__ __launch_bounds__(256) void scan_combine(
    float* __restrict__ S, const float* __restrict__ dtsum,
    const float* __restrict__ A_log) {
  int g = blockIdx.x * 256 + threadIdx.x;
  if (g >= BATCH * D_INNER) return;
  int b = g / D_INNER, d = g % D_INNER;
  float A[D_STATE];
#pragma unroll
  for (int s = 0; s < D_STATE; ++s) A[s] = -__expf(A_log[d * D_STATE + s]);
  float h[D_STATE];
#pragma unroll
  for (int s = 0; s < D_STATE; ++s) h[s] = 0.f;
  for (int c = 0; c < NC; ++c) {
    size_t base = (((size_t)b * NC + c) * D_STATE) * D_INNER + d;
    float dts = dtsum[((size_t)b * NC + c) * D_INNER + d];
#pragma unroll
    for (int s = 0; s < D_STATE; ++s) {
      size_t off = base + (size_t)s * D_INNER;
      float Sv = S[off];
      S[off] = h[s];                       // h_in for chunk c
      h[s] = __expf(dts * A[s]) * h[s] + Sv;
    }
  }
}

// ---------------------------------------------------------------------------
// Blocked selective scan, phase 3.  Applies bias+softplus to raw dt,
// computes y, D-skip, SiLU(z) gating; writes gated y as split bf16.
// ---------------------------------------------------------------------------
__global__ __launch_bounds__(256) void scan_chunk2(
    const float* __restrict__ dty, const float* __restrict__ u,
    const float* __restrict__ dbc, const float* __restrict__ xz,
    const float* __restrict__ A_log, const float* __restrict__ dtb,
    const float* __restrict__ Dv, const float* __restrict__ hin,
    short* __restrict__ y_hi, short* __restrict__ y_lo) {
  int g = blockIdx.x * 256 + threadIdx.x;
  if (g >= BATCH * NC * D_INNER) return;
  int d = g % D_INNER;
  int c = (g / D_INNER) % NC;
  int b = g / (D_INNER * NC);
  float A[D_STATE];
#pragma unroll
  for (int s = 0; s < D_STATE; ++s) A[s] = -__expf(A_log[d * D_STATE + s]);
  float bias = dtb[d];
  float Dval = Dv[d];
  float h[D_STATE];
  size_t hbase = (((size_t)b * NC + c) * D_STATE) * D_INNER + d;
#pragma unroll
  for (int s = 0; s < D_STATE; ++s) h[s] = hin[hbase + (size_t)s * D_INNER];
  int t0 = c * CHUNK_T;
  for (int t = t0; t < t0 + CHUNK_T; ++t) {
    size_t rowb = (size_t)b * SEQLEN + t;
    float dtv = softplusf(dty[rowb * D_INNER + d] + bias);
    float uv  = u[rowb * D_INNER + d];
    const float* bc = dbc + rowb * DBC_W;
    float dtu = dtv * uv;
    float yv = 0.f;
#pragma unroll
    for (int s = 0; s < D_STATE; ++s) {
      float da = __expf(dtv * A[s]);
      h[s] = da * h[s] + dtu * bc[DT_RANK + s];
      yv += h[s] * bc[DT_RANK + D_STATE + s];
    }
    float zv = xz[rowb * (2 * D_INNER) + D_INNER + d];
    float sig = 1.f / (1.f + __expf(-zv));
    float yo = (yv + uv * Dval) * (zv * sig);
    short hv, lv; split_bf16(yo, hv, lv);
    y_hi[rowb * D_INNER + d] = hv;
    y_lo[rowb * D_INNER + d] = lv;
  }
}

// ---------------------------------------------------------------------------
// Final: residual add + LN(normf) + LN(dec), last rtn tokens only.
// ---------------------------------------------------------------------------
__global__ __launch_bounds__(256) void final_kernel(
    const float* __restrict__ hy, const float* __restrict__ resid,
    const float* __restrict__ fw, const float* __restrict__ fb,
    const float* __restrict__ dw, const float* __restrict__ db,
    float* __restrict__ out, int rtn) {
  int rowo = blockIdx.x;                 // 0 .. BATCH*rtn-1
  int b = rowo / rtn;
  int t = SEQLEN - rtn + (rowo % rtn);
  int tid = threadIdx.x;
  size_t base = ((size_t)b * SEQLEN + t) * D_MODEL;
  __shared__ float red[256];
  __shared__ float s_mu1, s_rs1, s_mu2, s_rs2;
  float v[3];
#pragma unroll
  for (int i = 0; i < 3; ++i) {
    int c = tid + i * 256;
    v[i] = hy[base + c] + resid[base + c];
  }
  // --- LN 1 ---
  red[tid] = v[0] + v[1] + v[2]; __syncthreads();
  for (int off = 128; off > 0; off >>= 1) {
    if (tid < off) red[tid] += red[tid + off];
    __syncthreads();
  }
  if (tid == 0) s_mu1 = red[0] / D_MODEL;
  __syncthreads();
  float mu = s_mu1, q = 0.f;
#pragma unroll
  for (int i = 0; i < 3; ++i) { float dd = v[i] - mu; q += dd * dd; }
  __syncthreads();
  red[tid] = q; __syncthreads();
  for (int off = 128; off > 0; off >>= 1) {
    if (tid < off) red[tid] += red[tid + off];
    __syncthreads();
  }
  if (tid == 0) s_rs1 = rsqrtf(red[0] / D_MODEL + 1e-5f);
  __syncthreads();
  float rs = s_rs1;
#pragma unroll
  for (int i = 0; i < 3; ++i) {
    int c = tid + i * 256;
    v[i] = (v[i] - mu) * rs * fw[c] + fb[c];
  }
  // --- LN 2 ---
  __syncthreads();
  red[tid] = v[0] + v[1] + v[2]; __syncthreads();
  for (int off = 128; off > 0; off >>= 1) {
    if (tid < off) red[tid] += red[tid + off];
    __syncthreads();
  }
  if (tid == 0) s_mu2 = red[0] / D_MODEL;
  __syncthreads();
  mu = s_mu2; q = 0.f;
#pragma unroll
  for (int i = 0; i < 3; ++i) { float dd = v[i] - mu; q += dd * dd; }
  __syncthreads();
  red[tid] = q; __syncthreads();
  for (int off = 128; off > 0; off >>= 1) {
    if (tid < off) red[tid] += red[tid + off];
    __syncthreads();
  }
  if (tid == 0) s_rs2 = rsqrtf(red[0] / D_MODEL + 1e-5f);
  __syncthreads();
  rs = s_rs2;
#pragma unroll
  for (int i = 0; i < 3; ++i) {
    int c = tid + i * 256;
    out[(size_t)rowo * D_MODEL + c] = (v[i] - mu) * rs * dw[c] + db[c];
  }
}

// ---------------------------------------------------------------------------
extern "C" void kernel_launch(void* const* d_in, const int* in_sizes, int n_in,
                              void* d_out, int out_size, void* d_ws, size_t ws_size,
                              hipStream_t stream) {
  const float* x       = (const float*)d_in[0];
  const float* pos     = (const float*)d_in[1];
  const float* norm_w  = (const float*)d_in[2];
  const float* norm_b  = (const float*)d_in[3];
  const float* in_proj = (const float*)d_in[4];
  const float* conv_w  = (const float*)d_in[5];
  const float* conv_b  = (const float*)d_in[6];
  const float* x_proj  = (const float*)d_in[7];
  const float* dt_w    = (const float*)d_in[8];
  const float* dt_b    = (const float*)d_in[9];
  const float* A_log   = (const float*)d_in[10];
  const float* Dv      = (const float*)d_in[11];
  const float* out_proj= (const float*)d_in[12];
  const float* normf_w = (const float*)d_in[13];
  const float* normf_b = (const float*)d_in[14];
  const float* dec_w   = (const float*)d_in[15];
  const float* dec_b   = (const float*)d_in[16];
  int rtn = out_size / (BATCH * D_MODEL);   // return_token_num

  float* ws    = (float*)d_ws;
  float* resid = ws;                                 // NTOK*D_MODEL
  float* hy    = resid + (size_t)NTOK * D_MODEL;     // NTOK*D_MODEL (out_proj out)
  float* xz    = hy    + (size_t)NTOK * D_MODEL;     // NTOK*2*D_INNER
  float* u     = xz    + (size_t)NTOK * 2 * D_INNER; // NTOK*D_INNER
  float* dbc   = u     + (size_t)NTOK * D_INNER;     // NTOK*80
  float* dty   = dbc   + (size_t)NTOK * DBC_W;       // NTOK*D_INNER (raw dt)
  float* Sbuf  = dty   + (size_t)NTOK * D_INNER;     // BATCH*NC*D_STATE*D_INNER
  float* dtsum = Sbuf  + (size_t)BATCH * NC * D_STATE * D_INNER; // BATCH*NC*D_INNER
  short* hh_hi = (short*)(dtsum + (size_t)BATCH * NC * D_INNER);
  short* hh_lo = hh_hi + (size_t)NTOK * D_MODEL;
  short* y_hi  = hh_lo + (size_t)NTOK * D_MODEL;
  short* y_lo  = y_hi  + (size_t)NTOK * D_INNER;
  short* wbh   = y_lo  + (size_t)NTOK * D_INNER;     // 2*D_INNER*D_MODEL shorts
  short* wbl   = wbh   + (size_t)2 * D_INNER * D_MODEL;

  for (int l = 0; l < N_LAYER; ++l) {
    // split in_proj weights for this layer -> wbh/wbl
    split_kernel<<<1024, 256, 0, stream>>>(
        in_proj + (size_t)l * 2 * D_INNER * D_MODEL, wbh, wbl,
        2 * D_INNER * D_MODEL / 4);

    ln_kernel<<<NTOK, 256, 0, stream>>>(x, pos, resid, hy, hh_hi, hh_lo,
        norm_w + l * D_MODEL, norm_b + l * D_MODEL, l == 0);

    dim3 g1(2 * D_INNER / 128, NTOK / 128);
    gemm_bf16x3<<<g1, 256, 0, stream>>>(hh_hi, hh_lo, D_MODEL,
        wbh, wbl, D_MODEL, xz, NTOK, 2 * D_INNER, D_MODEL);

    conv_silu_kernel<<<(NTOK * D_INNER + 255) / 256, 256, 0, stream>>>(
        xz, conv_w + (size_t)l * D_INNER * D_CONV, conv_b + l * D_INNER, u);

    xproj_gemm<<<NTOK / 64, 256, 0, stream>>>(
        u, x_proj + (size_t)l * DBC_W * D_INNER, dbc);

    // dt raw scores: dbc[:, :48] @ dt_w^T  -> dty   (M=4096, N=1536, K=48)
    dim3 gdt(D_INNER / 128, NTOK / 128);
    gemm_abt<<<gdt, 256, 0, stream>>>(dbc, DBC_W,
        dt_w + (size_t)l * D_INNER * DT_RANK, DT_RANK, dty,
        NTOK, D_INNER, DT_RANK);

    const float* Al = A_log + (size_t)l * D_INNER * D_STATE;
    const float* dtbl = dt_b + (size_t)l * D_INNER;
    int tot1 = BATCH * NC * D_INNER;
    scan_chunk1<<<(tot1 + 255) / 256, 256, 0, stream>>>(
        dty, u, dbc, Al, dtbl, Sbuf, dtsum);
    scan_combine<<<(BATCH * D_INNER + 255) / 256, 256, 0, stream>>>(
        Sbuf, dtsum, Al);
    scan_chunk2<<<(tot1 + 255) / 256, 256, 0, stream>>>(
        dty, u, dbc, xz, Al, dtbl, Dv + l * D_INNER, Sbuf, y_hi, y_lo);

    // split out_proj weights for this layer -> wbh/wbl (reuse buffer)
    split_kernel<<<1024, 256, 0, stream>>>(
        out_proj + (size_t)l * D_MODEL * D_INNER, wbh, wbl,
        D_MODEL * D_INNER / 4);

    dim3 g2(D_MODEL / 128, NTOK / 128);
    gemm_bf16x3<<<g2, 256, 0, stream>>>(y_hi, y_lo, D_INNER,
        wbh, wbl, D_INNER, hy, NTOK, D_MODEL, D_INNER);
  }

  final_kernel<<<BATCH * rtn, 256, 0, stream>>>(
      hy, resid, normf_w, normf_b, dec_w, dec_b, (float*)d_out, rtn);
}

// Round 5
// 3371.533 us; speedup vs baseline: 5.6058x; 1.2789x over previous
//
#include <hip/hip_runtime.h>
#include <math.h>

#define D_MODEL 768
#define N_LAYER 8
#define D_INNER 1536
#define D_STATE 16
#define DT_RANK 48
#define D_CONV  4
#define BATCH   4
#define SEQLEN  1024
#define NTOK    (BATCH*SEQLEN)      // 4096 token rows
#define DBC_W   (DT_RANK + 2*D_STATE)  // 80
#define NC      32                  // scan chunks per sequence
#define CHUNK_T (SEQLEN/NC)         // 32 timesteps per chunk
#define XP_KS   8                   // xproj split-K slices
#define XP_KSL  (D_INNER/XP_KS)     // 192 k per slice

typedef __attribute__((ext_vector_type(8))) short short8v;   // 8 bf16 (4 VGPRs)
typedef __attribute__((ext_vector_type(4))) float float4v;   // 4 fp32 acc

// Split fp32 into hi+lo bf16 (both RNE).  x ~= hi + lo, |err| ~ 2^-17 |x|.
__device__ __forceinline__ void split_bf16(float x, short& hi, short& lo) {
  unsigned u = __float_as_uint(x);
  unsigned r = (u + 0x7fffu + ((u >> 16) & 1u)) >> 16;
  hi = (short)r;
  float fhi = __uint_as_float(r << 16);
  float xl = x - fhi;
  unsigned u2 = __float_as_uint(xl);
  unsigned r2 = (u2 + 0x7fffu + ((u2 >> 16) & 1u)) >> 16;
  lo = (short)r2;
}

// ---------------------------------------------------------------------------
// Weight split: fp32 [n] -> bf16 hi[n], lo[n].  n4 = n/4, float4-vectorized.
// ---------------------------------------------------------------------------
__global__ __launch_bounds__(256) void split_kernel(
    const float* __restrict__ src, short* __restrict__ hi,
    short* __restrict__ lo, int n4) {
  int stride = gridDim.x * 256;
  for (int i = blockIdx.x * 256 + threadIdx.x; i < n4; i += stride) {
    float4 v = ((const float4*)src)[i];
    short4 h, g;
    split_bf16(v.x, h.x, g.x);
    split_bf16(v.y, h.y, g.y);
    split_bf16(v.z, h.z, g.z);
    split_bf16(v.w, h.w, g.w);
    ((short4*)hi)[i] = h;
    ((short4*)lo)[i] = g;
  }
}

// ---------------------------------------------------------------------------
// Zero fp32 buffer (float4 granularity).
// ---------------------------------------------------------------------------
__global__ __launch_bounds__(256) void zero_kernel(float* __restrict__ p, int n4) {
  int i = blockIdx.x * 256 + threadIdx.x;
  if (i < n4) ((float4*)p)[i] = make_float4(0.f, 0.f, 0.f, 0.f);
}

// ---------------------------------------------------------------------------
// LayerNorm + residual update.  One block per token row (768 elems, 256 thr).
// first=1: resid = x + pos.  first=0: resid += hy (prev out_proj output).
// Writes normalized output as split bf16 (hh_hi/hh_lo) for the MFMA GEMM.
// ---------------------------------------------------------------------------
__global__ __launch_bounds__(256) void ln_kernel(
    const float* __restrict__ x, const float* __restrict__ pos,
    float* __restrict__ resid, const float* __restrict__ hy,
    short* __restrict__ hh_hi, short* __restrict__ hh_lo,
    const float* __restrict__ w, const float* __restrict__ b, int first) {
  int row = blockIdx.x;
  int tid = threadIdx.x;
  int base = row * D_MODEL;
  __shared__ float red[256];
  __shared__ float s_mu, s_rs;
  float v[3];
#pragma unroll
  for (int i = 0; i < 3; ++i) {
    int c = tid + i * 256;
    float r;
    if (first) r = x[base + c] + pos[base + c];
    else       r = resid[base + c] + hy[base + c];
    resid[base + c] = r;
    v[i] = r;
  }
  float s = v[0] + v[1] + v[2];
  red[tid] = s; __syncthreads();
  for (int off = 128; off > 0; off >>= 1) {
    if (tid < off) red[tid] += red[tid + off];
    __syncthreads();
  }
  if (tid == 0) s_mu = red[0] / D_MODEL;
  __syncthreads();
  float mu = s_mu;
  float q = 0.f;
#pragma unroll
  for (int i = 0; i < 3; ++i) { float d = v[i] - mu; q += d * d; }
  __syncthreads();
  red[tid] = q; __syncthreads();
  for (int off = 128; off > 0; off >>= 1) {
    if (tid < off) red[tid] += red[tid + off];
    __syncthreads();
  }
  if (tid == 0) s_rs = rsqrtf(red[0] / D_MODEL + 1e-5f);
  __syncthreads();
  float rs = s_rs;
#pragma unroll
  for (int i = 0; i < 3; ++i) {
    int c = tid + i * 256;
    float val = (v[i] - mu) * rs * w[c] + b[c];
    short hv, lv; split_bf16(val, hv, lv);
    hh_hi[base + c] = hv;
    hh_lo[base + c] = lv;
  }
}

// ---------------------------------------------------------------------------
// bf16x3 MFMA GEMM:  C[M][N] = A[M][K] . B[N][K]^T  (fp32-equivalent accuracy)
// A,B given as split bf16 (hi,lo).  Computes hi*hi + hi*lo + lo*hi.
// 128x128 tile, BK=32, 256 thr = 4 waves (2x2), 4x4 16x16x32 frags per wave.
// ---------------------------------------------------------------------------
__global__ __launch_bounds__(256) void gemm_bf16x3(
    const short* __restrict__ Ahi, const short* __restrict__ Alo, int lda,
    const short* __restrict__ Bhi, const short* __restrict__ Blo, int ldb,
    float* __restrict__ C, int M, int N, int K) {
  const int BK = 32, LDSS = 40;
  __shared__ short Ash[128][LDSS];
  __shared__ short Asl[128][LDSS];
  __shared__ short Bsh[128][LDSS];
  __shared__ short Bsl[128][LDSS];
  int brow = blockIdx.y * 128;
  int bcol = blockIdx.x * 128;
  int tid = threadIdx.x;
  int w = tid >> 6, l = tid & 63;
  int wr = (w >> 1) * 64;            // wave row origin in tile
  int wc = (w & 1) * 64;             // wave col origin in tile
  int lrow = l & 15;
  int lk = (l >> 4) * 8;             // k-offset of this lane's fragment
  float4v zero = {0.f, 0.f, 0.f, 0.f};
  float4v acc[4][4];
#pragma unroll
  for (int m = 0; m < 4; ++m)
#pragma unroll
    for (int n = 0; n < 4; ++n) acc[m][n] = zero;

  for (int k0 = 0; k0 < K; k0 += BK) {
#pragma unroll
    for (int it = 0; it < 2; ++it) {
      int idx = tid + it * 256;      // 0..511
      int r = idx >> 2;              // 0..127
      int q = (idx & 3) * 8;         // 0,8,16,24 (bf16 elems)
      *(uint4*)&Ash[r][q] = *(const uint4*)&Ahi[(size_t)(brow + r) * lda + k0 + q];
      *(uint4*)&Asl[r][q] = *(const uint4*)&Alo[(size_t)(brow + r) * lda + k0 + q];
      *(uint4*)&Bsh[r][q] = *(const uint4*)&Bhi[(size_t)(bcol + r) * ldb + k0 + q];
      *(uint4*)&Bsl[r][q] = *(const uint4*)&Blo[(size_t)(bcol + r) * ldb + k0 + q];
    }
    __syncthreads();
    short8v ah[4], al[4];
#pragma unroll
    for (int m = 0; m < 4; ++m) {
      ah[m] = *(const short8v*)&Ash[wr + m * 16 + lrow][lk];
      al[m] = *(const short8v*)&Asl[wr + m * 16 + lrow][lk];
    }
#pragma unroll
    for (int n = 0; n < 4; ++n) {
      short8v bh = *(const short8v*)&Bsh[wc + n * 16 + lrow][lk];
      short8v bl = *(const short8v*)&Bsl[wc + n * 16 + lrow][lk];
#pragma unroll
      for (int m = 0; m < 4; ++m) {
        acc[m][n] = __builtin_amdgcn_mfma_f32_16x16x32_bf16(ah[m], bh, acc[m][n], 0, 0, 0);
        acc[m][n] = __builtin_amdgcn_mfma_f32_16x16x32_bf16(ah[m], bl, acc[m][n], 0, 0, 0);
        acc[m][n] = __builtin_amdgcn_mfma_f32_16x16x32_bf16(al[m], bh, acc[m][n], 0, 0, 0);
      }
    }
    __syncthreads();
  }
  int drow = (l >> 4) * 4, dcol = l & 15;
#pragma unroll
  for (int m = 0; m < 4; ++m)
#pragma unroll
    for (int n = 0; n < 4; ++n)
#pragma unroll
      for (int j = 0; j < 4; ++j)
        C[(size_t)(brow + wr + m * 16 + drow + j) * N + bcol + wc + n * 16 + dcol] =
            acc[m][n][j];
}

// ---------------------------------------------------------------------------
// C[M x N] = A[M x K] * B[N x K]^T   (row-major, fp32, leading dims lda/ldb)
// Used only for the small dt projection (K=48).
// ---------------------------------------------------------------------------
__global__ __launch_bounds__(256) void gemm_abt(
    const float* __restrict__ A, int lda, const float* __restrict__ B, int ldb,
    float* __restrict__ C, int M, int N, int K) {
  const int BM = 128, BN = 128, BK = 16;
  __shared__ __align__(16) float As[BK][BM + 4];
  __shared__ __align__(16) float Bs[BK][BN + 4];
  int brow = blockIdx.y * BM;
  int bcol = blockIdx.x * BN;
  int tid = threadIdx.x;
  int tr = (tid / 16) * 4;   // 0..60
  int tc = (tid % 16) * 4;   // 0..60
  float acc[2][2][4][4] = {};   // [row-half][col-half][i][j]
  for (int k0 = 0; k0 < K; k0 += BK) {
#pragma unroll
    for (int it = 0; it < 2; ++it) {
      int idx = tid + it * 256;          // 0..511
      int r  = idx >> 2;                 // 0..127
      int cq = (idx & 3) * 4;            // 0,4,8,12
      float4 a = *(const float4*)&A[(size_t)(brow + r) * lda + k0 + cq];
      As[cq + 0][r] = a.x; As[cq + 1][r] = a.y;
      As[cq + 2][r] = a.z; As[cq + 3][r] = a.w;
      float4 b = *(const float4*)&B[(size_t)(bcol + r) * ldb + k0 + cq];
      Bs[cq + 0][r] = b.x; Bs[cq + 1][r] = b.y;
      Bs[cq + 2][r] = b.z; Bs[cq + 3][r] = b.w;
    }
    __syncthreads();
#pragma unroll
    for (int kk = 0; kk < BK; ++kk) {
      float4 a0 = *(const float4*)&As[kk][tr];
      float4 a1 = *(const float4*)&As[kk][tr + 64];
      float4 b0 = *(const float4*)&Bs[kk][tc];
      float4 b1 = *(const float4*)&Bs[kk][tc + 64];
      float ar[2][4] = {{a0.x, a0.y, a0.z, a0.w}, {a1.x, a1.y, a1.z, a1.w}};
      float br[2][4] = {{b0.x, b0.y, b0.z, b0.w}, {b1.x, b1.y, b1.z, b1.w}};
#pragma unroll
      for (int rh = 0; rh < 2; ++rh)
#pragma unroll
        for (int ch = 0; ch < 2; ++ch)
#pragma unroll
          for (int i = 0; i < 4; ++i)
#pragma unroll
            for (int j = 0; j < 4; ++j)
              acc[rh][ch][i][j] += ar[rh][i] * br[ch][j];
    }
    __syncthreads();
  }
#pragma unroll
  for (int rh = 0; rh < 2; ++rh)
#pragma unroll
    for (int i = 0; i < 4; ++i) {
      int row = brow + tr + rh * 64 + i;
#pragma unroll
      for (int ch = 0; ch < 2; ++ch) {
        float4 o = make_float4(acc[rh][ch][i][0], acc[rh][ch][i][1],
                               acc[rh][ch][i][2], acc[rh][ch][i][3]);
        *(float4*)&C[(size_t)row * N + bcol + tc + ch * 64] = o;
      }
    }
}

// ---------------------------------------------------------------------------
// dbc[M=4096][80] += u[4096][1536] . xp[80][1536]^T  (split-K, atomic accum)
// blockIdx.x: 64-row tile; blockIdx.y: K-slice of 192.  512 blocks total.
// dbc must be zeroed first.
// ---------------------------------------------------------------------------
__global__ __launch_bounds__(256) void xproj_gemm(
    const float* __restrict__ u, const float* __restrict__ xp,
    float* __restrict__ dbc) {
  const int BM = 64, BK = 64;
  __shared__ float As[BK][BM + 1];     // stride 65
  __shared__ float Bs[BK][DBC_W + 1];  // stride 81
  int brow = blockIdx.x * BM;
  int kbase = blockIdx.y * XP_KSL;
  int tid = threadIdx.x;
  int tr = (tid / 16) * 4;    // 0..60
  int tc = (tid % 16) * 5;    // 0..75
  float acc[4][5] = {};
  for (int k0 = kbase; k0 < kbase + XP_KSL; k0 += BK) {
#pragma unroll
    for (int it = 0; it < 4; ++it) {           // A: 64 rows x 64 k
      int lin = tid + it * 256;                // 0..1023
      int r  = lin >> 4;                       // 0..63
      int kq = (lin & 15) * 4;
      float4 a = *(const float4*)&u[(size_t)(brow + r) * D_INNER + k0 + kq];
      As[kq + 0][r] = a.x; As[kq + 1][r] = a.y;
      As[kq + 2][r] = a.z; As[kq + 3][r] = a.w;
    }
#pragma unroll
    for (int it = 0; it < 5; ++it) {           // B: 80 rows x 64 k
      int lin = tid + it * 256;                // 0..1279
      int e  = lin >> 4;                       // 0..79
      int kq = (lin & 15) * 4;
      float4 b = *(const float4*)&xp[(size_t)e * D_INNER + k0 + kq];
      Bs[kq + 0][e] = b.x; Bs[kq + 1][e] = b.y;
      Bs[kq + 2][e] = b.z; Bs[kq + 3][e] = b.w;
    }
    __syncthreads();
#pragma unroll
    for (int kk = 0; kk < BK; ++kk) {
      float ar[4], br[5];
#pragma unroll
      for (int i = 0; i < 4; ++i) ar[i] = As[kk][tr + i];
#pragma unroll
      for (int j = 0; j < 5; ++j) br[j] = Bs[kk][tc + j];
#pragma unroll
      for (int i = 0; i < 4; ++i)
#pragma unroll
        for (int j = 0; j < 5; ++j) acc[i][j] += ar[i] * br[j];
    }
    __syncthreads();
  }
#pragma unroll
  for (int i = 0; i < 4; ++i)
#pragma unroll
    for (int j = 0; j < 5; ++j)
      atomicAdd(&dbc[(size_t)(brow + tr + i) * DBC_W + tc + j], acc[i][j]);
}

// ---------------------------------------------------------------------------
// Causal depthwise conv (width 4) + bias + SiLU.  xm = xz[..., :D_INNER].
// ---------------------------------------------------------------------------
__global__ __launch_bounds__(256) void conv_silu_kernel(
    const float* __restrict__ xz, const float* __restrict__ cw,
    const float* __restrict__ cb, float* __restrict__ u) {
  int idx = blockIdx.x * 256 + threadIdx.x;
  if (idx >= NTOK * D_INNER) return;
  int c = idx % D_INNER;
  int t = (idx / D_INNER) % SEQLEN;
  int b = idx / (D_INNER * SEQLEN);
  float acc = cb[c];
#pragma unroll
  for (int k = 0; k < D_CONV; ++k) {
    int tt = t + k - (D_CONV - 1);
    if (tt >= 0)
      acc += xz[(size_t)(b * SEQLEN + tt) * (2 * D_INNER) + c] * cw[c * D_CONV + k];
  }
  float sig = 1.f / (1.f + __expf(-acc));
  u[idx] = acc * sig;
}

__device__ __forceinline__ float softplusf(float a) {
  return (a > 20.f) ? a : log1pf(__expf(a));
}

// ---------------------------------------------------------------------------
// Blocked selective scan, phase 1.  dty holds RAW dt scores (pre-bias,
// pre-softplus); bias+softplus applied here on the fly.
// ---------------------------------------------------------------------------
__global__ __launch_bounds__(256) void scan_chunk1(
    const float* __restrict__ dty, const float* __restrict__ u,
    const float* __restrict__ dbc, const float* __restrict__ A_log,
    const float* __restrict__ dtb,
    float* __restrict__ S, float* __restrict__ dtsum) {
  int g = blockIdx.x * 256 + threadIdx.x;
  if (g >= BATCH * NC * D_INNER) return;
  int d = g % D_INNER;
  int c = (g / D_INNER) % NC;
  int b = g / (D_INNER * NC);
  float A[D_STATE];
#pragma unroll
  for (int s = 0; s < D_STATE; ++s) A[s] = -__expf(A_log[d * D_STATE + s]);
  float bias = dtb[d];
  float h[D_STATE];
#pragma unroll
  for (int s = 0; s < D_STATE; ++s) h[s] = 0.f;
  float dts = 0.f;
  int t0 = c * CHUNK_T;
  for (int t = t0; t < t0 + CHUNK_T; ++t) {
    size_t rowb = (size_t)b * SEQLEN + t;
    float dtv = softplusf(dty[rowb * D_INNER + d] + bias);
    float uv  = u[rowb * D_INNER + d];
    const float* bc = dbc + rowb * DBC_W;
    float dtu = dtv * uv;
    dts += dtv;
#pragma unroll
    for (int s = 0; s < D_STATE; ++s) {
      float da = __expf(dtv * A[s]);
      h[s] = da * h[s] + dtu * bc[DT_RANK + s];
    }
  }
  size_t base = (((size_t)b * NC + c) * D_STATE) * D_INNER + d;
#pragma unroll
  for (int s = 0; s < D_STATE; ++s) S[base + (size_t)s * D_INNER] = h[s];
  dtsum[((size_t)b * NC + c) * D_INNER + d] = dts;
}

// ---------------------------------------------------------------------------
// Blocked selective scan, phase 2 (serial chunk combine, tiny).
// ---------------------------------------------------------------------------
__global__ __launch_bounds__(256) void scan_combine(
    float* __restrict__ S, const float* __restrict__ dtsum,
    const float* __restrict__ A_log) {
  int g = blockIdx.x * 256 + threadIdx.x;
  if (g >= BATCH * D_INNER) return;
  int b = g / D_INNER, d = g % D_INNER;
  float A[D_STATE];
#pragma unroll
  for (int s = 0; s < D_STATE; ++s) A[s] = -__expf(A_log[d * D_STATE + s]);
  float h[D_STATE];
#pragma unroll
  for (int s = 0; s < D_STATE; ++s) h[s] = 0.f;
  for (int c = 0; c < NC; ++c) {
    size_t base = (((size_t)b * NC + c) * D_STATE) * D_INNER + d;
    float dts = dtsum[((size_t)b * NC + c) * D_INNER + d];
#pragma unroll
    for (int s = 0; s < D_STATE; ++s) {
      size_t off = base + (size_t)s * D_INNER;
      float Sv = S[off];
      S[off] = h[s];                       // h_in for chunk c
      h[s] = __expf(dts * A[s]) * h[s] + Sv;
    }
  }
}

// ---------------------------------------------------------------------------
// Blocked selective scan, phase 3.  Applies bias+softplus to raw dt,
// computes y, D-skip, SiLU(z) gating; writes gated y as split bf16.
// ---------------------------------------------------------------------------
__global__ __launch_bounds__(256) void scan_chunk2(
    const float* __restrict__ dty, const float* __restrict__ u,
    const float* __restrict__ dbc, const float* __restrict__ xz,
    const float* __restrict__ A_log, const float* __restrict__ dtb,
    const float* __restrict__ Dv, const float* __restrict__ hin,
    short* __restrict__ y_hi, short* __restrict__ y_lo) {
  int g = blockIdx.x * 256 + threadIdx.x;
  if (g >= BATCH * NC * D_INNER) return;
  int d = g % D_INNER;
  int c = (g / D_INNER) % NC;
  int b = g / (D_INNER * NC);
  float A[D_STATE];
#pragma unroll
  for (int s = 0; s < D_STATE; ++s) A[s] = -__expf(A_log[d * D_STATE + s]);
  float bias = dtb[d];
  float Dval = Dv[d];
  float h[D_STATE];
  size_t hbase = (((size_t)b * NC + c) * D_STATE) * D_INNER + d;
#pragma unroll
  for (int s = 0; s < D_STATE; ++s) h[s] = hin[hbase + (size_t)s * D_INNER];
  int t0 = c * CHUNK_T;
  for (int t = t0; t < t0 + CHUNK_T; ++t) {
    size_t rowb = (size_t)b * SEQLEN + t;
    float dtv = softplusf(dty[rowb * D_INNER + d] + bias);
    float uv  = u[rowb * D_INNER + d];
    const float* bc = dbc + rowb * DBC_W;
    float dtu = dtv * uv;
    float yv = 0.f;
#pragma unroll
    for (int s = 0; s < D_STATE; ++s) {
      float da = __expf(dtv * A[s]);
      h[s] = da * h[s] + dtu * bc[DT_RANK + s];
      yv += h[s] * bc[DT_RANK + D_STATE + s];
    }
    float zv = xz[rowb * (2 * D_INNER) + D_INNER + d];
    float sig = 1.f / (1.f + __expf(-zv));
    float yo = (yv + uv * Dval) * (zv * sig);
    short hv, lv; split_bf16(yo, hv, lv);
    y_hi[rowb * D_INNER + d] = hv;
    y_lo[rowb * D_INNER + d] = lv;
  }
}

// ---------------------------------------------------------------------------
// Final: residual add + LN(normf) + LN(dec), last rtn tokens only.
// ---------------------------------------------------------------------------
__global__ __launch_bounds__(256) void final_kernel(
    const float* __restrict__ hy, const float* __restrict__ resid,
    const float* __restrict__ fw, const float* __restrict__ fb,
    const float* __restrict__ dw, const float* __restrict__ db,
    float* __restrict__ out, int rtn) {
  int rowo = blockIdx.x;                 // 0 .. BATCH*rtn-1
  int b = rowo / rtn;
  int t = SEQLEN - rtn + (rowo % rtn);
  int tid = threadIdx.x;
  size_t base = ((size_t)b * SEQLEN + t) * D_MODEL;
  __shared__ float red[256];
  __shared__ float s_mu1, s_rs1, s_mu2, s_rs2;
  float v[3];
#pragma unroll
  for (int i = 0; i < 3; ++i) {
    int c = tid + i * 256;
    v[i] = hy[base + c] + resid[base + c];
  }
  // --- LN 1 ---
  red[tid] = v[0] + v[1] + v[2]; __syncthreads();
  for (int off = 128; off > 0; off >>= 1) {
    if (tid < off) red[tid] += red[tid + off];
    __syncthreads();
  }
  if (tid == 0) s_mu1 = red[0] / D_MODEL;
  __syncthreads();
  float mu = s_mu1, q = 0.f;
#pragma unroll
  for (int i = 0; i < 3; ++i) { float dd = v[i] - mu; q += dd * dd; }
  __syncthreads();
  red[tid] = q; __syncthreads();
  for (int off = 128; off > 0; off >>= 1) {
    if (tid < off) red[tid] += red[tid + off];
    __syncthreads();
  }
  if (tid == 0) s_rs1 = rsqrtf(red[0] / D_MODEL + 1e-5f);
  __syncthreads();
  float rs = s_rs1;
#pragma unroll
  for (int i = 0; i < 3; ++i) {
    int c = tid + i * 256;
    v[i] = (v[i] - mu) * rs * fw[c] + fb[c];
  }
  // --- LN 2 ---
  __syncthreads();
  red[tid] = v[0] + v[1] + v[2]; __syncthreads();
  for (int off = 128; off > 0; off >>= 1) {
    if (tid < off) red[tid] += red[tid + off];
    __syncthreads();
  }
  if (tid == 0) s_mu2 = red[0] / D_MODEL;
  __syncthreads();
  mu = s_mu2; q = 0.f;
#pragma unroll
  for (int i = 0; i < 3; ++i) { float dd = v[i] - mu; q += dd * dd; }
  __syncthreads();
  red[tid] = q; __syncthreads();
  for (int off = 128; off > 0; off >>= 1) {
    if (tid < off) red[tid] += red[tid + off];
    __syncthreads();
  }
  if (tid == 0) s_rs2 = rsqrtf(red[0] / D_MODEL + 1e-5f);
  __syncthreads();
  rs = s_rs2;
#pragma unroll
  for (int i = 0; i < 3; ++i) {
    int c = tid + i * 256;
    out[(size_t)rowo * D_MODEL + c] = (v[i] - mu) * rs * dw[c] + db[c];
  }
}

// ---------------------------------------------------------------------------
extern "C" void kernel_launch(void* const* d_in, const int* in_sizes, int n_in,
                              void* d_out, int out_size, void* d_ws, size_t ws_size,
                              hipStream_t stream) {
  const float* x       = (const float*)d_in[0];
  const float* pos     = (const float*)d_in[1];
  const float* norm_w  = (const float*)d_in[2];
  const float* norm_b  = (const float*)d_in[3];
  const float* in_proj = (const float*)d_in[4];
  const float* conv_w  = (const float*)d_in[5];
  const float* conv_b  = (const float*)d_in[6];
  const float* x_proj  = (const float*)d_in[7];
  const float* dt_w    = (const float*)d_in[8];
  const float* dt_b    = (const float*)d_in[9];
  const float* A_log   = (const float*)d_in[10];
  const float* Dv      = (const float*)d_in[11];
  const float* out_proj= (const float*)d_in[12];
  const float* normf_w = (const float*)d_in[13];
  const float* normf_b = (const float*)d_in[14];
  const float* dec_w   = (const float*)d_in[15];
  const float* dec_b   = (const float*)d_in[16];
  int rtn = out_size / (BATCH * D_MODEL);   // return_token_num

  float* ws    = (float*)d_ws;
  float* resid = ws;                                 // NTOK*D_MODEL
  float* hy    = resid + (size_t)NTOK * D_MODEL;     // NTOK*D_MODEL (out_proj out)
  float* xz    = hy    + (size_t)NTOK * D_MODEL;     // NTOK*2*D_INNER
  float* u     = xz    + (size_t)NTOK * 2 * D_INNER; // NTOK*D_INNER
  float* dbc   = u     + (size_t)NTOK * D_INNER;     // NTOK*80
  float* dty   = dbc   + (size_t)NTOK * DBC_W;       // NTOK*D_INNER (raw dt)
  float* Sbuf  = dty   + (size_t)NTOK * D_INNER;     // BATCH*NC*D_STATE*D_INNER
  float* dtsum = Sbuf  + (size_t)BATCH * NC * D_STATE * D_INNER; // BATCH*NC*D_INNER
  short* hh_hi = (short*)(dtsum + (size_t)BATCH * NC * D_INNER);
  short* hh_lo = hh_hi + (size_t)NTOK * D_MODEL;
  short* y_hi  = hh_lo + (size_t)NTOK * D_MODEL;
  short* y_lo  = y_hi  + (size_t)NTOK * D_INNER;
  short* wbh   = y_lo  + (size_t)NTOK * D_INNER;     // 2*D_INNER*D_MODEL shorts
  short* wbl   = wbh   + (size_t)2 * D_INNER * D_MODEL;

  for (int l = 0; l < N_LAYER; ++l) {
    // split in_proj weights for this layer -> wbh/wbl
    split_kernel<<<1024, 256, 0, stream>>>(
        in_proj + (size_t)l * 2 * D_INNER * D_MODEL, wbh, wbl,
        2 * D_INNER * D_MODEL / 4);

    ln_kernel<<<NTOK, 256, 0, stream>>>(x, pos, resid, hy, hh_hi, hh_lo,
        norm_w + l * D_MODEL, norm_b + l * D_MODEL, l == 0);

    dim3 g1(2 * D_INNER / 128, NTOK / 128);
    gemm_bf16x3<<<g1, 256, 0, stream>>>(hh_hi, hh_lo, D_MODEL,
        wbh, wbl, D_MODEL, xz, NTOK, 2 * D_INNER, D_MODEL);

    conv_silu_kernel<<<(NTOK * D_INNER + 255) / 256, 256, 0, stream>>>(
        xz, conv_w + (size_t)l * D_INNER * D_CONV, conv_b + l * D_INNER, u);

    zero_kernel<<<(NTOK * DBC_W / 4 + 255) / 256, 256, 0, stream>>>(
        dbc, NTOK * DBC_W / 4);
    dim3 gxp(NTOK / 64, XP_KS);
    xproj_gemm<<<gxp, 256, 0, stream>>>(
        u, x_proj + (size_t)l * DBC_W * D_INNER, dbc);

    // dt raw scores: dbc[:, :48] @ dt_w^T  -> dty   (M=4096, N=1536, K=48)
    dim3 gdt(D_INNER / 128, NTOK / 128);
    gemm_abt<<<gdt, 256, 0, stream>>>(dbc, DBC_W,
        dt_w + (size_t)l * D_INNER * DT_RANK, DT_RANK, dty,
        NTOK, D_INNER, DT_RANK);

    const float* Al = A_log + (size_t)l * D_INNER * D_STATE;
    const float* dtbl = dt_b + (size_t)l * D_INNER;
    int tot1 = BATCH * NC * D_INNER;
    scan_chunk1<<<(tot1 + 255) / 256, 256, 0, stream>>>(
        dty, u, dbc, Al, dtbl, Sbuf, dtsum);
    scan_combine<<<(BATCH * D_INNER + 255) / 256, 256, 0, stream>>>(
        Sbuf, dtsum, Al);
    scan_chunk2<<<(tot1 + 255) / 256, 256, 0, stream>>>(
        dty, u, dbc, xz, Al, dtbl, Dv + l * D_INNER, Sbuf, y_hi, y_lo);

    // split out_proj weights for this layer -> wbh/wbl (reuse buffer)
    split_kernel<<<1024, 256, 0, stream>>>(
        out_proj + (size_t)l * D_MODEL * D_INNER, wbh, wbl,
        D_MODEL * D_INNER / 4);

    dim3 g2(D_MODEL / 128, NTOK / 128);
    gemm_bf16x3<<<g2, 256, 0, stream>>>(y_hi, y_lo, D_INNER,
        wbh, wbl, D_INNER, hy, NTOK, D_MODEL, D_INNER);
  }

  final_kernel<<<BATCH * rtn, 256, 0, stream>>>(
      hy, resid, normf_w, normf_b, dec_w, dec_b, (float*)d_out, rtn);
}

// Round 6
// 3221.176 us; speedup vs baseline: 5.8675x; 1.0467x over previous
//
#include <hip/hip_runtime.h>
#include <math.h>

#define D_MODEL 768
#define N_LAYER 8
#define D_INNER 1536
#define D_STATE 16
#define DT_RANK 48
#define D_CONV  4
#define BATCH   4
#define SEQLEN  1024
#define NTOK    (BATCH*SEQLEN)      // 4096 token rows
#define DBC_W   (DT_RANK + 2*D_STATE)  // 80
#define NC      32                  // scan chunks per sequence
#define CHUNK_T (SEQLEN/NC)         // 32 timesteps per chunk
#define XP_KS   8                   // xproj split-K slices
#define XP_KSL  (D_INNER/XP_KS)     // 192 k per slice

typedef __attribute__((ext_vector_type(8))) short short8v;   // 8 bf16 (4 VGPRs)
typedef __attribute__((ext_vector_type(4))) float float4v;   // 4 fp32 acc

// Split fp32 into hi+lo bf16 (both RNE).  x ~= hi + lo, |err| ~ 2^-17 |x|.
__device__ __forceinline__ void split_bf16(float x, short& hi, short& lo) {
  unsigned u = __float_as_uint(x);
  unsigned r = (u + 0x7fffu + ((u >> 16) & 1u)) >> 16;
  hi = (short)r;
  float fhi = __uint_as_float(r << 16);
  float xl = x - fhi;
  unsigned u2 = __float_as_uint(xl);
  unsigned r2 = (u2 + 0x7fffu + ((u2 >> 16) & 1u)) >> 16;
  lo = (short)r2;
}

// ---------------------------------------------------------------------------
// Weight split: fp32 [n] -> bf16 hi[n], lo[n].  n4 = n/4, float4-vectorized.
// ---------------------------------------------------------------------------
__global__ __launch_bounds__(256) void split_kernel(
    const float* __restrict__ src, short* __restrict__ hi,
    short* __restrict__ lo, int n4) {
  int stride = gridDim.x * 256;
  for (int i = blockIdx.x * 256 + threadIdx.x; i < n4; i += stride) {
    float4 v = ((const float4*)src)[i];
    short4 h, g;
    split_bf16(v.x, h.x, g.x);
    split_bf16(v.y, h.y, g.y);
    split_bf16(v.z, h.z, g.z);
    split_bf16(v.w, h.w, g.w);
    ((short4*)hi)[i] = h;
    ((short4*)lo)[i] = g;
  }
}

// ---------------------------------------------------------------------------
// LayerNorm + residual update.  One block per token row (768 elems, 256 thr).
// first=1: resid = x + pos.  first=0: resid += hy (prev out_proj output).
// Writes normalized output as split bf16 (hh_hi/hh_lo) for the MFMA GEMM.
// ---------------------------------------------------------------------------
__global__ __launch_bounds__(256) void ln_kernel(
    const float* __restrict__ x, const float* __restrict__ pos,
    float* __restrict__ resid, const float* __restrict__ hy,
    short* __restrict__ hh_hi, short* __restrict__ hh_lo,
    const float* __restrict__ w, const float* __restrict__ b, int first) {
  int row = blockIdx.x;
  int tid = threadIdx.x;
  int base = row * D_MODEL;
  __shared__ float red[256];
  __shared__ float s_mu, s_rs;
  float v[3];
#pragma unroll
  for (int i = 0; i < 3; ++i) {
    int c = tid + i * 256;
    float r;
    if (first) r = x[base + c] + pos[base + c];
    else       r = resid[base + c] + hy[base + c];
    resid[base + c] = r;
    v[i] = r;
  }
  float s = v[0] + v[1] + v[2];
  red[tid] = s; __syncthreads();
  for (int off = 128; off > 0; off >>= 1) {
    if (tid < off) red[tid] += red[tid + off];
    __syncthreads();
  }
  if (tid == 0) s_mu = red[0] / D_MODEL;
  __syncthreads();
  float mu = s_mu;
  float q = 0.f;
#pragma unroll
  for (int i = 0; i < 3; ++i) { float d = v[i] - mu; q += d * d; }
  __syncthreads();
  red[tid] = q; __syncthreads();
  for (int off = 128; off > 0; off >>= 1) {
    if (tid < off) red[tid] += red[tid + off];
    __syncthreads();
  }
  if (tid == 0) s_rs = rsqrtf(red[0] / D_MODEL + 1e-5f);
  __syncthreads();
  float rs = s_rs;
#pragma unroll
  for (int i = 0; i < 3; ++i) {
    int c = tid + i * 256;
    float val = (v[i] - mu) * rs * w[c] + b[c];
    short hv, lv; split_bf16(val, hv, lv);
    hh_hi[base + c] = hv;
    hh_lo[base + c] = lv;
  }
}

// ---------------------------------------------------------------------------
// bf16x3 MFMA GEMM:  C[M][N] = A[M][K] . B[N][K]^T  (fp32-equivalent accuracy)
// A,B given as split bf16 (hi,lo).  Computes hi*hi + hi*lo + lo*hi.
// 128x128 tile, BK=32, 256 thr = 4 waves (2x2), 4x4 16x16x32 frags per wave.
// ---------------------------------------------------------------------------
__global__ __launch_bounds__(256) void gemm_bf16x3(
    const short* __restrict__ Ahi, const short* __restrict__ Alo, int lda,
    const short* __restrict__ Bhi, const short* __restrict__ Blo, int ldb,
    float* __restrict__ C, int M, int N, int K) {
  const int BK = 32, LDSS = 40;
  __shared__ short Ash[128][LDSS];
  __shared__ short Asl[128][LDSS];
  __shared__ short Bsh[128][LDSS];
  __shared__ short Bsl[128][LDSS];
  int brow = blockIdx.y * 128;
  int bcol = blockIdx.x * 128;
  int tid = threadIdx.x;
  int w = tid >> 6, l = tid & 63;
  int wr = (w >> 1) * 64;            // wave row origin in tile
  int wc = (w & 1) * 64;             // wave col origin in tile
  int lrow = l & 15;
  int lk = (l >> 4) * 8;             // k-offset of this lane's fragment
  float4v zero = {0.f, 0.f, 0.f, 0.f};
  float4v acc[4][4];
#pragma unroll
  for (int m = 0; m < 4; ++m)
#pragma unroll
    for (int n = 0; n < 4; ++n) acc[m][n] = zero;

  for (int k0 = 0; k0 < K; k0 += BK) {
#pragma unroll
    for (int it = 0; it < 2; ++it) {
      int idx = tid + it * 256;      // 0..511
      int r = idx >> 2;              // 0..127
      int q = (idx & 3) * 8;         // 0,8,16,24 (bf16 elems)
      *(uint4*)&Ash[r][q] = *(const uint4*)&Ahi[(size_t)(brow + r) * lda + k0 + q];
      *(uint4*)&Asl[r][q] = *(const uint4*)&Alo[(size_t)(brow + r) * lda + k0 + q];
      *(uint4*)&Bsh[r][q] = *(const uint4*)&Bhi[(size_t)(bcol + r) * ldb + k0 + q];
      *(uint4*)&Bsl[r][q] = *(const uint4*)&Blo[(size_t)(bcol + r) * ldb + k0 + q];
    }
    __syncthreads();
    short8v ah[4], al[4];
#pragma unroll
    for (int m = 0; m < 4; ++m) {
      ah[m] = *(const short8v*)&Ash[wr + m * 16 + lrow][lk];
      al[m] = *(const short8v*)&Asl[wr + m * 16 + lrow][lk];
    }
#pragma unroll
    for (int n = 0; n < 4; ++n) {
      short8v bh = *(const short8v*)&Bsh[wc + n * 16 + lrow][lk];
      short8v bl = *(const short8v*)&Bsl[wc + n * 16 + lrow][lk];
#pragma unroll
      for (int m = 0; m < 4; ++m) {
        acc[m][n] = __builtin_amdgcn_mfma_f32_16x16x32_bf16(ah[m], bh, acc[m][n], 0, 0, 0);
        acc[m][n] = __builtin_amdgcn_mfma_f32_16x16x32_bf16(ah[m], bl, acc[m][n], 0, 0, 0);
        acc[m][n] = __builtin_amdgcn_mfma_f32_16x16x32_bf16(al[m], bh, acc[m][n], 0, 0, 0);
      }
    }
    __syncthreads();
  }
  int drow = (l >> 4) * 4, dcol = l & 15;
#pragma unroll
  for (int m = 0; m < 4; ++m)
#pragma unroll
    for (int n = 0; n < 4; ++n)
#pragma unroll
      for (int j = 0; j < 4; ++j)
        C[(size_t)(brow + wr + m * 16 + drow + j) * N + bcol + wc + n * 16 + dcol] =
            acc[m][n][j];
}

// ---------------------------------------------------------------------------
// C[M x N] = A[M x K] * B[N x K]^T   (row-major, fp32, leading dims lda/ldb)
// Used only for the small dt projection (K=48).
// ---------------------------------------------------------------------------
__global__ __launch_bounds__(256) void gemm_abt(
    const float* __restrict__ A, int lda, const float* __restrict__ B, int ldb,
    float* __restrict__ C, int M, int N, int K) {
  const int BM = 128, BN = 128, BK = 16;
  __shared__ __align__(16) float As[BK][BM + 4];
  __shared__ __align__(16) float Bs[BK][BN + 4];
  int brow = blockIdx.y * BM;
  int bcol = blockIdx.x * BN;
  int tid = threadIdx.x;
  int tr = (tid / 16) * 4;   // 0..60
  int tc = (tid % 16) * 4;   // 0..60
  float acc[2][2][4][4] = {};   // [row-half][col-half][i][j]
  for (int k0 = 0; k0 < K; k0 += BK) {
#pragma unroll
    for (int it = 0; it < 2; ++it) {
      int idx = tid + it * 256;          // 0..511
      int r  = idx >> 2;                 // 0..127
      int cq = (idx & 3) * 4;            // 0,4,8,12
      float4 a = *(const float4*)&A[(size_t)(brow + r) * lda + k0 + cq];
      As[cq + 0][r] = a.x; As[cq + 1][r] = a.y;
      As[cq + 2][r] = a.z; As[cq + 3][r] = a.w;
      float4 b = *(const float4*)&B[(size_t)(bcol + r) * ldb + k0 + cq];
      Bs[cq + 0][r] = b.x; Bs[cq + 1][r] = b.y;
      Bs[cq + 2][r] = b.z; Bs[cq + 3][r] = b.w;
    }
    __syncthreads();
#pragma unroll
    for (int kk = 0; kk < BK; ++kk) {
      float4 a0 = *(const float4*)&As[kk][tr];
      float4 a1 = *(const float4*)&As[kk][tr + 64];
      float4 b0 = *(const float4*)&Bs[kk][tc];
      float4 b1 = *(const float4*)&Bs[kk][tc + 64];
      float ar[2][4] = {{a0.x, a0.y, a0.z, a0.w}, {a1.x, a1.y, a1.z, a1.w}};
      float br[2][4] = {{b0.x, b0.y, b0.z, b0.w}, {b1.x, b1.y, b1.z, b1.w}};
#pragma unroll
      for (int rh = 0; rh < 2; ++rh)
#pragma unroll
        for (int ch = 0; ch < 2; ++ch)
#pragma unroll
          for (int i = 0; i < 4; ++i)
#pragma unroll
            for (int j = 0; j < 4; ++j)
              acc[rh][ch][i][j] += ar[rh][i] * br[ch][j];
    }
    __syncthreads();
  }
#pragma unroll
  for (int rh = 0; rh < 2; ++rh)
#pragma unroll
    for (int i = 0; i < 4; ++i) {
      int row = brow + tr + rh * 64 + i;
#pragma unroll
      for (int ch = 0; ch < 2; ++ch) {
        float4 o = make_float4(acc[rh][ch][i][0], acc[rh][ch][i][1],
                               acc[rh][ch][i][2], acc[rh][ch][i][3]);
        *(float4*)&C[(size_t)row * N + bcol + tc + ch * 64] = o;
      }
    }
}

// ---------------------------------------------------------------------------
// part[slice][M=4096][80] = u[.,kslice] . xp[.,kslice]^T  (split-K, no atomics)
// blockIdx.x: 64-row tile; blockIdx.y: K-slice of 192.  512 blocks total.
// ---------------------------------------------------------------------------
__global__ __launch_bounds__(256) void xproj_gemm(
    const float* __restrict__ u, const float* __restrict__ xp,
    float* __restrict__ part) {
  const int BM = 64, BK = 64;
  __shared__ float As[BK][BM + 1];     // stride 65
  __shared__ float Bs[BK][DBC_W + 1];  // stride 81
  int brow = blockIdx.x * BM;
  int kbase = blockIdx.y * XP_KSL;
  int tid = threadIdx.x;
  int tr = (tid / 16) * 4;    // 0..60
  int tc = (tid % 16) * 5;    // 0..75
  float acc[4][5] = {};
  for (int k0 = kbase; k0 < kbase + XP_KSL; k0 += BK) {
#pragma unroll
    for (int it = 0; it < 4; ++it) {           // A: 64 rows x 64 k
      int lin = tid + it * 256;                // 0..1023
      int r  = lin >> 4;                       // 0..63
      int kq = (lin & 15) * 4;
      float4 a = *(const float4*)&u[(size_t)(brow + r) * D_INNER + k0 + kq];
      As[kq + 0][r] = a.x; As[kq + 1][r] = a.y;
      As[kq + 2][r] = a.z; As[kq + 3][r] = a.w;
    }
#pragma unroll
    for (int it = 0; it < 5; ++it) {           // B: 80 rows x 64 k
      int lin = tid + it * 256;                // 0..1279
      int e  = lin >> 4;                       // 0..79
      int kq = (lin & 15) * 4;
      float4 b = *(const float4*)&xp[(size_t)e * D_INNER + k0 + kq];
      Bs[kq + 0][e] = b.x; Bs[kq + 1][e] = b.y;
      Bs[kq + 2][e] = b.z; Bs[kq + 3][e] = b.w;
    }
    __syncthreads();
#pragma unroll
    for (int kk = 0; kk < BK; ++kk) {
      float ar[4], br[5];
#pragma unroll
      for (int i = 0; i < 4; ++i) ar[i] = As[kk][tr + i];
#pragma unroll
      for (int j = 0; j < 5; ++j) br[j] = Bs[kk][tc + j];
#pragma unroll
      for (int i = 0; i < 4; ++i)
#pragma unroll
        for (int j = 0; j < 5; ++j) acc[i][j] += ar[i] * br[j];
    }
    __syncthreads();
  }
  float* dst = part + (size_t)blockIdx.y * NTOK * DBC_W;
#pragma unroll
  for (int i = 0; i < 4; ++i)
#pragma unroll
    for (int j = 0; j < 5; ++j)
      dst[(size_t)(brow + tr + i) * DBC_W + tc + j] = acc[i][j];
}

// ---------------------------------------------------------------------------
// dbc = sum over XP_KS slices of part.  float4-vectorized.
// ---------------------------------------------------------------------------
__global__ __launch_bounds__(256) void reduce_dbc_kernel(
    const float* __restrict__ part, float* __restrict__ dbc, int n4) {
  int i = blockIdx.x * 256 + threadIdx.x;
  if (i >= n4) return;
  float4 s = ((const float4*)part)[i];
#pragma unroll
  for (int k = 1; k < XP_KS; ++k) {
    float4 v = ((const float4*)(part + (size_t)k * NTOK * DBC_W))[i];
    s.x += v.x; s.y += v.y; s.z += v.z; s.w += v.w;
  }
  ((float4*)dbc)[i] = s;
}

// ---------------------------------------------------------------------------
// Causal depthwise conv (width 4) + bias + SiLU.  xm = xz[..., :D_INNER].
// ---------------------------------------------------------------------------
__global__ __launch_bounds__(256) void conv_silu_kernel(
    const float* __restrict__ xz, const float* __restrict__ cw,
    const float* __restrict__ cb, float* __restrict__ u) {
  int idx = blockIdx.x * 256 + threadIdx.x;
  if (idx >= NTOK * D_INNER) return;
  int c = idx % D_INNER;
  int t = (idx / D_INNER) % SEQLEN;
  int b = idx / (D_INNER * SEQLEN);
  float acc = cb[c];
#pragma unroll
  for (int k = 0; k < D_CONV; ++k) {
    int tt = t + k - (D_CONV - 1);
    if (tt >= 0)
      acc += xz[(size_t)(b * SEQLEN + tt) * (2 * D_INNER) + c] * cw[c * D_CONV + k];
  }
  float sig = 1.f / (1.f + __expf(-acc));
  u[idx] = acc * sig;
}

__device__ __forceinline__ float softplusf(float a) {
  return (a > 20.f) ? a : log1pf(__expf(a));
}

// ---------------------------------------------------------------------------
// Blocked selective scan, phase 1.  dty holds RAW dt scores (pre-bias,
// pre-softplus); bias+softplus applied here on the fly.
// ---------------------------------------------------------------------------
__global__ __launch_bounds__(256) void scan_chunk1(
    const float* __restrict__ dty, const float* __restrict__ u,
    const float* __restrict__ dbc, const float* __restrict__ A_log,
    const float* __restrict__ dtb,
    float* __restrict__ S, float* __restrict__ dtsum) {
  int g = blockIdx.x * 256 + threadIdx.x;
  if (g >= BATCH * NC * D_INNER) return;
  int d = g % D_INNER;
  int c = (g / D_INNER) % NC;
  int b = g / (D_INNER * NC);
  float A[D_STATE];
#pragma unroll
  for (int s = 0; s < D_STATE; ++s) A[s] = -__expf(A_log[d * D_STATE + s]);
  float bias = dtb[d];
  float h[D_STATE];
#pragma unroll
  for (int s = 0; s < D_STATE; ++s) h[s] = 0.f;
  float dts = 0.f;
  int t0 = c * CHUNK_T;
  for (int t = t0; t < t0 + CHUNK_T; ++t) {
    size_t rowb = (size_t)b * SEQLEN + t;
    float dtv = softplusf(dty[rowb * D_INNER + d] + bias);
    float uv  = u[rowb * D_INNER + d];
    const float* bc = dbc + rowb * DBC_W;
    float dtu = dtv * uv;
    dts += dtv;
#pragma unroll
    for (int s = 0; s < D_STATE; ++s) {
      float da = __expf(dtv * A[s]);
      h[s] = da * h[s] + dtu * bc[DT_RANK + s];
    }
  }
  size_t base = (((size_t)b * NC + c) * D_STATE) * D_INNER + d;
#pragma unroll
  for (int s = 0; s < D_STATE; ++s) S[base + (size_t)s * D_INNER] = h[s];
  dtsum[((size_t)b * NC + c) * D_INNER + d] = dts;
}

// ---------------------------------------------------------------------------
// Blocked selective scan, phase 2 (serial chunk combine, tiny).
// ---------------------------------------------------------------------------
__global__ __launch_bounds__(256) void scan_combine(
    float* __restrict__ S, const float* __restrict__ dtsum,
    const float* __restrict__ A_log) {
  int g = blockIdx.x * 256 + threadIdx.x;
  if (g >= BATCH * D_INNER) return;
  int b = g / D_INNER, d = g % D_INNER;
  float A[D_STATE];
#pragma unroll
  for (int s = 0; s < D_STATE; ++s) A[s] = -__expf(A_log[d * D_STATE + s]);
  float h[D_STATE];
#pragma unroll
  for (int s = 0; s < D_STATE; ++s) h[s] = 0.f;
  for (int c = 0; c < NC; ++c) {
    size_t base = (((size_t)b * NC + c) * D_STATE) * D_INNER + d;
    float dts = dtsum[((size_t)b * NC + c) * D_INNER + d];
#pragma unroll
    for (int s = 0; s < D_STATE; ++s) {
      size_t off = base + (size_t)s * D_INNER;
      float Sv = S[off];
      S[off] = h[s];                       // h_in for chunk c
      h[s] = __expf(dts * A[s]) * h[s] + Sv;
    }
  }
}

// ---------------------------------------------------------------------------
// Blocked selective scan, phase 3.  Applies bias+softplus to raw dt,
// computes y, D-skip, SiLU(z) gating; writes gated y as split bf16.
// ---------------------------------------------------------------------------
__global__ __launch_bounds__(256) void scan_chunk2(
    const float* __restrict__ dty, const float* __restrict__ u,
    const float* __restrict__ dbc, const float* __restrict__ xz,
    const float* __restrict__ A_log, const float* __restrict__ dtb,
    const float* __restrict__ Dv, const float* __restrict__ hin,
    short* __restrict__ y_hi, short* __restrict__ y_lo) {
  int g = blockIdx.x * 256 + threadIdx.x;
  if (g >= BATCH * NC * D_INNER) return;
  int d = g % D_INNER;
  int c = (g / D_INNER) % NC;
  int b = g / (D_INNER * NC);
  float A[D_STATE];
#pragma unroll
  for (int s = 0; s < D_STATE; ++s) A[s] = -__expf(A_log[d * D_STATE + s]);
  float bias = dtb[d];
  float Dval = Dv[d];
  float h[D_STATE];
  size_t hbase = (((size_t)b * NC + c) * D_STATE) * D_INNER + d;
#pragma unroll
  for (int s = 0; s < D_STATE; ++s) h[s] = hin[hbase + (size_t)s * D_INNER];
  int t0 = c * CHUNK_T;
  for (int t = t0; t < t0 + CHUNK_T; ++t) {
    size_t rowb = (size_t)b * SEQLEN + t;
    float dtv = softplusf(dty[rowb * D_INNER + d] + bias);
    float uv  = u[rowb * D_INNER + d];
    const float* bc = dbc + rowb * DBC_W;
    float dtu = dtv * uv;
    float yv = 0.f;
#pragma unroll
    for (int s = 0; s < D_STATE; ++s) {
      float da = __expf(dtv * A[s]);
      h[s] = da * h[s] + dtu * bc[DT_RANK + s];
      yv += h[s] * bc[DT_RANK + D_STATE + s];
    }
    float zv = xz[rowb * (2 * D_INNER) + D_INNER + d];
    float sig = 1.f / (1.f + __expf(-zv));
    float yo = (yv + uv * Dval) * (zv * sig);
    short hv, lv; split_bf16(yo, hv, lv);
    y_hi[rowb * D_INNER + d] = hv;
    y_lo[rowb * D_INNER + d] = lv;
  }
}

// ---------------------------------------------------------------------------
// Final: residual add + LN(normf) + LN(dec), last rtn tokens only.
// ---------------------------------------------------------------------------
__global__ __launch_bounds__(256) void final_kernel(
    const float* __restrict__ hy, const float* __restrict__ resid,
    const float* __restrict__ fw, const float* __restrict__ fb,
    const float* __restrict__ dw, const float* __restrict__ db,
    float* __restrict__ out, int rtn) {
  int rowo = blockIdx.x;                 // 0 .. BATCH*rtn-1
  int b = rowo / rtn;
  int t = SEQLEN - rtn + (rowo % rtn);
  int tid = threadIdx.x;
  size_t base = ((size_t)b * SEQLEN + t) * D_MODEL;
  __shared__ float red[256];
  __shared__ float s_mu1, s_rs1, s_mu2, s_rs2;
  float v[3];
#pragma unroll
  for (int i = 0; i < 3; ++i) {
    int c = tid + i * 256;
    v[i] = hy[base + c] + resid[base + c];
  }
  // --- LN 1 ---
  red[tid] = v[0] + v[1] + v[2]; __syncthreads();
  for (int off = 128; off > 0; off >>= 1) {
    if (tid < off) red[tid] += red[tid + off];
    __syncthreads();
  }
  if (tid == 0) s_mu1 = red[0] / D_MODEL;
  __syncthreads();
  float mu = s_mu1, q = 0.f;
#pragma unroll
  for (int i = 0; i < 3; ++i) { float dd = v[i] - mu; q += dd * dd; }
  __syncthreads();
  red[tid] = q; __syncthreads();
  for (int off = 128; off > 0; off >>= 1) {
    if (tid < off) red[tid] += red[tid + off];
    __syncthreads();
  }
  if (tid == 0) s_rs1 = rsqrtf(red[0] / D_MODEL + 1e-5f);
  __syncthreads();
  float rs = s_rs1;
#pragma unroll
  for (int i = 0; i < 3; ++i) {
    int c = tid + i * 256;
    v[i] = (v[i] - mu) * rs * fw[c] + fb[c];
  }
  // --- LN 2 ---
  __syncthreads();
  red[tid] = v[0] + v[1] + v[2]; __syncthreads();
  for (int off = 128; off > 0; off >>= 1) {
    if (tid < off) red[tid] += red[tid + off];
    __syncthreads();
  }
  if (tid == 0) s_mu2 = red[0] / D_MODEL;
  __syncthreads();
  mu = s_mu2; q = 0.f;
#pragma unroll
  for (int i = 0; i < 3; ++i) { float dd = v[i] - mu; q += dd * dd; }
  __syncthreads();
  red[tid] = q; __syncthreads();
  for (int off = 128; off > 0; off >>= 1) {
    if (tid < off) red[tid] += red[tid + off];
    __syncthreads();
  }
  if (tid == 0) s_rs2 = rsqrtf(red[0] / D_MODEL + 1e-5f);
  __syncthreads();
  rs = s_rs2;
#pragma unroll
  for (int i = 0; i < 3; ++i) {
    int c = tid + i * 256;
    out[(size_t)rowo * D_MODEL + c] = (v[i] - mu) * rs * dw[c] + db[c];
  }
}

// ---------------------------------------------------------------------------
extern "C" void kernel_launch(void* const* d_in, const int* in_sizes, int n_in,
                              void* d_out, int out_size, void* d_ws, size_t ws_size,
                              hipStream_t stream) {
  const float* x       = (const float*)d_in[0];
  const float* pos     = (const float*)d_in[1];
  const float* norm_w  = (const float*)d_in[2];
  const float* norm_b  = (const float*)d_in[3];
  const float* in_proj = (const float*)d_in[4];
  const float* conv_w  = (const float*)d_in[5];
  const float* conv_b  = (const float*)d_in[6];
  const float* x_proj  = (const float*)d_in[7];
  const float* dt_w    = (const float*)d_in[8];
  const float* dt_b    = (const float*)d_in[9];
  const float* A_log   = (const float*)d_in[10];
  const float* Dv      = (const float*)d_in[11];
  const float* out_proj= (const float*)d_in[12];
  const float* normf_w = (const float*)d_in[13];
  const float* normf_b = (const float*)d_in[14];
  const float* dec_w   = (const float*)d_in[15];
  const float* dec_b   = (const float*)d_in[16];
  int rtn = out_size / (BATCH * D_MODEL);   // return_token_num

  float* ws    = (float*)d_ws;
  float* resid = ws;                                 // NTOK*D_MODEL
  float* hy    = resid + (size_t)NTOK * D_MODEL;     // NTOK*D_MODEL (out_proj out)
  float* xz    = hy    + (size_t)NTOK * D_MODEL;     // NTOK*2*D_INNER
  float* u     = xz    + (size_t)NTOK * 2 * D_INNER; // NTOK*D_INNER
  float* dbc   = u     + (size_t)NTOK * D_INNER;     // NTOK*80
  float* dty   = dbc   + (size_t)NTOK * DBC_W;       // NTOK*D_INNER (raw dt)
  float* Sbuf  = dty   + (size_t)NTOK * D_INNER;     // BATCH*NC*D_STATE*D_INNER
  float* dtsum = Sbuf  + (size_t)BATCH * NC * D_STATE * D_INNER; // BATCH*NC*D_INNER
  float* dbcp  = dtsum + (size_t)BATCH * NC * D_INNER; // XP_KS*NTOK*DBC_W
  short* hh_hi = (short*)(dbcp + (size_t)XP_KS * NTOK * DBC_W);
  short* hh_lo = hh_hi + (size_t)NTOK * D_MODEL;
  short* y_hi  = hh_lo + (size_t)NTOK * D_MODEL;
  short* y_lo  = y_hi  + (size_t)NTOK * D_INNER;
  short* wbh   = y_lo  + (size_t)NTOK * D_INNER;     // 2*D_INNER*D_MODEL shorts
  short* wbl   = wbh   + (size_t)2 * D_INNER * D_MODEL;

  for (int l = 0; l < N_LAYER; ++l) {
    // split in_proj weights for this layer -> wbh/wbl
    split_kernel<<<1024, 256, 0, stream>>>(
        in_proj + (size_t)l * 2 * D_INNER * D_MODEL, wbh, wbl,
        2 * D_INNER * D_MODEL / 4);

    ln_kernel<<<NTOK, 256, 0, stream>>>(x, pos, resid, hy, hh_hi, hh_lo,
        norm_w + l * D_MODEL, norm_b + l * D_MODEL, l == 0);

    dim3 g1(2 * D_INNER / 128, NTOK / 128);
    gemm_bf16x3<<<g1, 256, 0, stream>>>(hh_hi, hh_lo, D_MODEL,
        wbh, wbl, D_MODEL, xz, NTOK, 2 * D_INNER, D_MODEL);

    conv_silu_kernel<<<(NTOK * D_INNER + 255) / 256, 256, 0, stream>>>(
        xz, conv_w + (size_t)l * D_INNER * D_CONV, conv_b + l * D_INNER, u);

    dim3 gxp(NTOK / 64, XP_KS);
    xproj_gemm<<<gxp, 256, 0, stream>>>(
        u, x_proj + (size_t)l * DBC_W * D_INNER, dbcp);
    reduce_dbc_kernel<<<(NTOK * DBC_W / 4 + 255) / 256, 256, 0, stream>>>(
        dbcp, dbc, NTOK * DBC_W / 4);

    // dt raw scores: dbc[:, :48] @ dt_w^T  -> dty   (M=4096, N=1536, K=48)
    dim3 gdt(D_INNER / 128, NTOK / 128);
    gemm_abt<<<gdt, 256, 0, stream>>>(dbc, DBC_W,
        dt_w + (size_t)l * D_INNER * DT_RANK, DT_RANK, dty,
        NTOK, D_INNER, DT_RANK);

    const float* Al = A_log + (size_t)l * D_INNER * D_STATE;
    const float* dtbl = dt_b + (size_t)l * D_INNER;
    int tot1 = BATCH * NC * D_INNER;
    scan_chunk1<<<(tot1 + 255) / 256, 256, 0, stream>>>(
        dty, u, dbc, Al, dtbl, Sbuf, dtsum);
    scan_combine<<<(BATCH * D_INNER + 255) / 256, 256, 0, stream>>>(
        Sbuf, dtsum, Al);
    scan_chunk2<<<(tot1 + 255) / 256, 256, 0, stream>>>(
        dty, u, dbc, xz, Al, dtbl, Dv + l * D_INNER, Sbuf, y_hi, y_lo);

    // split out_proj weights for this layer -> wbh/wbl (reuse buffer)
    split_kernel<<<1024, 256, 0, stream>>>(
        out_proj + (size_t)l * D_MODEL * D_INNER, wbh, wbl,
        D_MODEL * D_INNER / 4);

    dim3 g2(D_MODEL / 128, NTOK / 128);
    gemm_bf16x3<<<g2, 256, 0, stream>>>(y_hi, y_lo, D_INNER,
        wbh, wbl, D_INNER, hy, NTOK, D_MODEL, D_INNER);
  }

  final_kernel<<<BATCH * rtn, 256, 0, stream>>>(
      hy, resid, normf_w, normf_b, dec_w, dec_b, (float*)d_out, rtn);
}